// Round 2
// baseline (699.074 us; speedup 1.0000x reference)
//
#include <hip/hip_runtime.h>
#include <hip/hip_bf16.h>
#include <math.h>

#define DIM 64
#define GNUM 256
#define CNUM 10

// ---------------- utility ----------------
__global__ void zero_kernel(int* __restrict__ p, int n) {
    int i = blockIdx.x * blockDim.x + threadIdx.x;
    if (i < n) p[i] = 0;
}

// ---------------- CSR build ----------------
__global__ void deg_kernel(const int* __restrict__ ei, int E, int N, int* __restrict__ deg) {
    int i = blockIdx.x * blockDim.x + threadIdx.x;
    int EP = E + N;
    if (i >= EP) return;
    int d = (i < E) ? ei[E + i] : (i - E);   // row 1 of edge_index = dst; self loops appended
    atomicAdd(&deg[d], 1);
}

__global__ __launch_bounds__(1024) void scan_excl(const int* __restrict__ deg, int* __restrict__ offs, int n) {
    __shared__ int wsum[16];
    __shared__ int carry_s;
    int tid = threadIdx.x;
    int lane = tid & 63;
    int wid = tid >> 6;
    if (tid == 0) carry_s = 0;
    __syncthreads();
    for (int base = 0; base < n; base += 1024) {
        int i = base + tid;
        int v = (i < n) ? deg[i] : 0;
        int x = v;
        #pragma unroll
        for (int d = 1; d < 64; d <<= 1) { int t = __shfl_up(x, d); if (lane >= d) x += t; }
        if (lane == 63) wsum[wid] = x;
        __syncthreads();
        if (wid == 0) {
            int s = (lane < 16) ? wsum[lane] : 0;
            #pragma unroll
            for (int d = 1; d < 16; d <<= 1) { int t = __shfl_up(s, d); if (lane >= d) s += t; }
            if (lane < 16) wsum[lane] = s;
        }
        __syncthreads();
        int woff = (wid > 0) ? wsum[wid - 1] : 0;
        if (i < n) offs[i] = carry_s + woff + x - v;   // exclusive
        __syncthreads();
        if (tid == 1023) carry_s += wsum[15];
        __syncthreads();
    }
    if (threadIdx.x == 0) offs[n] = carry_s;
}

__global__ void fill_kernel(const int* __restrict__ ei, int E, int N,
                            const int* __restrict__ offs, int* __restrict__ cursor,
                            int* __restrict__ csr_src) {
    int i = blockIdx.x * blockDim.x + threadIdx.x;
    int EP = E + N;
    if (i >= EP) return;
    int s, d;
    if (i < E) { s = ei[i]; d = ei[E + i]; } else { s = i - E; d = i - E; }
    int p = offs[d] + atomicAdd(&cursor[d], 1);
    csr_src[p] = s;
}

// ---------------- h = in @ W ; alpha_s = h.a_s ; alpha_d = h.a_d ----------------
__global__ __launch_bounds__(256) void mm_alpha(const float* __restrict__ in, const float* __restrict__ W,
                                                const float* __restrict__ a_s, const float* __restrict__ a_d,
                                                float* __restrict__ h, float* __restrict__ as_,
                                                float* __restrict__ ad_, int N) {
    __shared__ float Ws[DIM * DIM];
    __shared__ float asv[DIM], adv[DIM];
    int tid = threadIdx.x;
    for (int k = tid; k < DIM * DIM; k += 256) Ws[k] = W[k];
    if (tid < DIM) { asv[tid] = a_s[tid]; adv[tid] = a_d[tid]; }
    __syncthreads();
    int lane = tid & 63, wid = tid >> 6;
    int row = blockIdx.x * 4 + wid;
    if (row >= N) return;
    float xv = in[row * DIM + lane];
    float acc = 0.f;
    #pragma unroll
    for (int k = 0; k < DIM; ++k) acc += __shfl(xv, k) * Ws[k * DIM + lane];
    h[row * DIM + lane] = acc;
    float s1 = acc * asv[lane], s2 = acc * adv[lane];
    #pragma unroll
    for (int m = 32; m >= 1; m >>= 1) { s1 += __shfl_xor(s1, m); s2 += __shfl_xor(s2, m); }
    if (lane == 0) { as_[row] = s1; ad_[row] = s2; }
}

// ---------------- per-node softmax-aggregate + bias + l2norm + relu ----------------
__global__ __launch_bounds__(256) void gat_agg(const float* __restrict__ h, const float* __restrict__ as_,
                                               const float* __restrict__ ad_, const int* __restrict__ offs,
                                               const int* __restrict__ csr, const float* __restrict__ bias,
                                               float* __restrict__ out, int N) {
    int tid = threadIdx.x, lane = tid & 63, wid = tid >> 6;
    int node = blockIdx.x * 4 + wid;
    if (node >= N) return;
    int start = offs[node], end = offs[node + 1];
    float adi = ad_[node];
    // pass 1: segment max (lane-parallel over edges)
    float m = -1e30f;
    for (int t = start + lane; t < end; t += 64) {
        float e = as_[csr[t]] + adi;
        e = (e > 0.f) ? e : 0.2f * e;
        m = fmaxf(m, e);
    }
    #pragma unroll
    for (int d = 32; d >= 1; d >>= 1) m = fmaxf(m, __shfl_xor(m, d));
    // pass 2: sequential over edges, lanes = features
    float s = 0.f, acc = 0.f;
    for (int t = start; t < end; ++t) {
        int src = csr[t];
        float e = as_[src] + adi;
        e = (e > 0.f) ? e : 0.2f * e;
        float w = expf(e - m);
        s += w;
        acc += w * h[src * DIM + lane];
    }
    float o = acc / (s + 1e-16f) + bias[lane];
    float n2 = o * o;
    #pragma unroll
    for (int d = 32; d >= 1; d >>= 1) n2 += __shfl_xor(n2, d);
    float nrm = fmaxf(sqrtf(n2), 1e-12f);
    out[node * DIM + lane] = fmaxf(o / nrm, 0.f);
}

// ---------------- pooling ----------------
__global__ void graph_bounds(const int* __restrict__ batch, int N, int* __restrict__ gstart) {
    int g = threadIdx.x;
    if (g > GNUM) return;
    int lo = 0, hi = N;
    while (lo < hi) { int mid = (lo + hi) >> 1; if (batch[mid] < g) lo = mid + 1; else hi = mid; }
    gstart[g] = lo;
}

#define POOL_CHUNK 8
__global__ __launch_bounds__(64) void pool_kernel(const float* __restrict__ h, const int* __restrict__ gstart,
                                                  float* __restrict__ g) {
    int gid = blockIdx.x / POOL_CHUNK, c = blockIdx.x % POOL_CHUNK;
    int lane = threadIdx.x;
    int s = gstart[gid], e = gstart[gid + 1];
    float acc = 0.f;
    for (int i = s + c; i < e; i += POOL_CHUNK) acc += h[i * DIM + lane];
    atomicAdd(&g[gid * DIM + lane], acc);
}

// ---------------- MLP head + log_softmax ----------------
__global__ __launch_bounds__(64) void mlp_kernel(const float* __restrict__ g,
                                                 const float* __restrict__ fc1w, const float* __restrict__ fc1b,
                                                 const float* __restrict__ fc2w, const float* __restrict__ fc2b,
                                                 float* __restrict__ out) {
    __shared__ float W1[DIM * DIM];
    __shared__ float tbuf[DIM];
    __shared__ float obuf[CNUM];
    int lane = threadIdx.x, gid = blockIdx.x;
    for (int k = lane; k < DIM * DIM; k += 64) W1[k] = fc1w[k];
    __syncthreads();
    float gv = g[gid * DIM + lane];
    float t = fc1b[lane];
    #pragma unroll
    for (int k = 0; k < DIM; ++k) t += __shfl(gv, k) * W1[k * DIM + lane];
    t = fmaxf(t, 0.f);
    tbuf[lane] = t;
    __syncthreads();
    if (lane < CNUM) {
        float o = fc2b[lane];
        #pragma unroll
        for (int k = 0; k < DIM; ++k) o += tbuf[k] * fc2w[k * CNUM + lane];
        obuf[lane] = o;
    }
    __syncthreads();
    if (lane < CNUM) {
        float mx = obuf[0];
        #pragma unroll
        for (int k = 1; k < CNUM; ++k) mx = fmaxf(mx, obuf[k]);
        float s = 0.f;
        #pragma unroll
        for (int k = 0; k < CNUM; ++k) s += expf(obuf[k] - mx);
        out[gid * CNUM + lane] = obuf[lane] - mx - logf(s);
    }
}

// ---------------- launch ----------------
static inline size_t align256(size_t x) { return (x + 255) & ~size_t(255); }

extern "C" void kernel_launch(void* const* d_in, const int* in_sizes, int n_in,
                              void* d_out, int out_size, void* d_ws, size_t ws_size,
                              hipStream_t stream) {
    const float* x     = (const float*)d_in[0];
    const int*   ei    = (const int*)d_in[1];
    const int*   batch = (const int*)d_in[2];
    const float* w1  = (const float*)d_in[3];
    const float* as1 = (const float*)d_in[4];
    const float* ad1 = (const float*)d_in[5];
    const float* b1  = (const float*)d_in[6];
    const float* w2  = (const float*)d_in[7];
    const float* as2 = (const float*)d_in[8];
    const float* ad2 = (const float*)d_in[9];
    const float* b2  = (const float*)d_in[10];
    const float* w3  = (const float*)d_in[11];
    const float* as3 = (const float*)d_in[12];
    const float* ad3 = (const float*)d_in[13];
    const float* b3  = (const float*)d_in[14];
    const float* fc1w = (const float*)d_in[15];
    const float* fc1b = (const float*)d_in[16];
    const float* fc2w = (const float*)d_in[17];
    const float* fc2b = (const float*)d_in[18];
    float* out = (float*)d_out;

    int N  = in_sizes[0] / DIM;
    int E  = in_sizes[1] / 2;
    int EP = E + N;

    // workspace carve
    char* p = (char*)d_ws;
    float* hA   = (float*)p; p += align256(sizeof(float) * (size_t)N * DIM);
    float* hB   = (float*)p; p += align256(sizeof(float) * (size_t)N * DIM);
    float* as_  = (float*)p; p += align256(sizeof(float) * (size_t)N);
    float* ad_  = (float*)p; p += align256(sizeof(float) * (size_t)N);
    int*   deg  = (int*)p;   p += align256(sizeof(int) * (size_t)N);
    int*   cur  = (int*)p;   p += align256(sizeof(int) * (size_t)N);
    int*   offs = (int*)p;   p += align256(sizeof(int) * (size_t)(N + 1));
    int*   csr  = (int*)p;   p += align256(sizeof(int) * (size_t)EP);
    int*   gst  = (int*)p;   p += align256(sizeof(int) * (size_t)(GNUM + 1));
    float* gpl  = (float*)p; p += align256(sizeof(float) * GNUM * DIM);

    int nblk = (N + 3) / 4;

    // CSR build (dst-grouped; layer-invariant)
    // NOTE: deg and cur are 256B-aligned carves — zero them SEPARATELY
    // (a single 2N-zero pass misses the tail of cur past the align pad;
    // 0xAA poison there caused the R0 OOB crash in fill_kernel).
    zero_kernel<<<(N + 255) / 256, 256, 0, stream>>>(deg, N);
    zero_kernel<<<(N + 255) / 256, 256, 0, stream>>>(cur, N);
    deg_kernel<<<(EP + 255) / 256, 256, 0, stream>>>(ei, E, N, deg);
    scan_excl<<<1, 1024, 0, stream>>>(deg, offs, N);
    fill_kernel<<<(EP + 255) / 256, 256, 0, stream>>>(ei, E, N, offs, cur, csr);
    graph_bounds<<<1, 512, 0, stream>>>(batch, N, gst);

    // layer 1
    mm_alpha<<<nblk, 256, 0, stream>>>(x, w1, as1, ad1, hA, as_, ad_, N);
    gat_agg<<<nblk, 256, 0, stream>>>(hA, as_, ad_, offs, csr, b1, hB, N);
    // layer 2
    mm_alpha<<<nblk, 256, 0, stream>>>(hB, w2, as2, ad2, hA, as_, ad_, N);
    gat_agg<<<nblk, 256, 0, stream>>>(hA, as_, ad_, offs, csr, b2, hB, N);
    // layer 3
    mm_alpha<<<nblk, 256, 0, stream>>>(hB, w3, as3, ad3, hA, as_, ad_, N);
    gat_agg<<<nblk, 256, 0, stream>>>(hA, as_, ad_, offs, csr, b3, hB, N);

    // pool + head
    zero_kernel<<<(GNUM * DIM + 255) / 256, 256, 0, stream>>>((int*)gpl, GNUM * DIM);
    pool_kernel<<<GNUM * POOL_CHUNK, 64, 0, stream>>>(hB, gst, gpl);
    mlp_kernel<<<GNUM, 64, 0, stream>>>(gpl, fc1w, fc1b, fc2w, fc2b, out);
}

// Round 3
// 523.492 us; speedup vs baseline: 1.3354x; 1.3354x over previous
//
#include <hip/hip_runtime.h>
#include <hip/hip_bf16.h>
#include <math.h>

#define DIM 64
#define GNUM 256
#define CNUM 10

// ---------------- utility ----------------
__global__ void zero2_kernel(int* __restrict__ a, int* __restrict__ b, int n) {
    int i = blockIdx.x * blockDim.x + threadIdx.x;
    if (i < n) { a[i] = 0; b[i] = 0; }
}
__global__ void zero_kernel(int* __restrict__ p, int n) {
    int i = blockIdx.x * blockDim.x + threadIdx.x;
    if (i < n) p[i] = 0;
}

// ---------------- CSR build ----------------
__global__ void deg_kernel(const int* __restrict__ ei, int E, int N, int* __restrict__ deg) {
    int i = blockIdx.x * blockDim.x + threadIdx.x;
    int EP = E + N;
    if (i >= EP) return;
    int d = (i < E) ? ei[E + i] : (i - E);   // row 1 of edge_index = dst; self loops appended
    atomicAdd(&deg[d], 1);
}

// 3-phase parallel exclusive scan over deg[0..n) -> offs[0..n]
__global__ __launch_bounds__(256) void scan_blocks(const int* __restrict__ deg, int* __restrict__ part, int n) {
    __shared__ int ws[4];
    int i = blockIdx.x * 256 + threadIdx.x;
    int v = (i < n) ? deg[i] : 0;
    #pragma unroll
    for (int d = 32; d >= 1; d >>= 1) v += __shfl_xor(v, d);
    if ((threadIdx.x & 63) == 0) ws[threadIdx.x >> 6] = v;
    __syncthreads();
    if (threadIdx.x == 0) part[blockIdx.x] = ws[0] + ws[1] + ws[2] + ws[3];
}

__global__ __launch_bounds__(256) void scan_top(int* __restrict__ part, int nb) {
    // exclusive scan of part[0..nb) in place; nb <= 256
    int tid = threadIdx.x, lane = tid & 63, wid = tid >> 6;
    __shared__ int ws[4];
    int v = (tid < nb) ? part[tid] : 0;
    int x = v;
    #pragma unroll
    for (int d = 1; d < 64; d <<= 1) { int t = __shfl_up(x, d); if (lane >= d) x += t; }
    if (lane == 63) ws[wid] = x;
    __syncthreads();
    int add = 0;
    for (int w = 0; w < wid; ++w) add += ws[w];
    if (tid < nb) part[tid] = add + x - v;
}

__global__ __launch_bounds__(256) void scan_down(const int* __restrict__ deg, const int* __restrict__ part,
                                                 int* __restrict__ offs, int n) {
    __shared__ int ws[4];
    int tid = threadIdx.x, lane = tid & 63, wid = tid >> 6;
    int i = blockIdx.x * 256 + tid;
    int v = (i < n) ? deg[i] : 0;
    int x = v;
    #pragma unroll
    for (int d = 1; d < 64; d <<= 1) { int t = __shfl_up(x, d); if (lane >= d) x += t; }
    if (lane == 63) ws[wid] = x;
    __syncthreads();
    int add = part[blockIdx.x];
    for (int w = 0; w < wid; ++w) add += ws[w];
    if (i < n) offs[i] = add + x - v;
    if (i == n - 1) offs[n] = add + x;
}

__global__ void fill_kernel(const int* __restrict__ ei, int E, int N,
                            const int* __restrict__ offs, int* __restrict__ cursor,
                            int* __restrict__ csr_src) {
    int i = blockIdx.x * blockDim.x + threadIdx.x;
    int EP = E + N;
    if (i >= EP) return;
    int s, d;
    if (i < E) { s = ei[i]; d = ei[E + i]; } else { s = i - E; d = i - E; }
    int p = offs[d] + atomicAdd(&cursor[d], 1);
    csr_src[p] = s;
}

// ---------------- h = in @ W ; alpha_s = h.a_s ; alpha_d = h.a_d ----------------
__global__ __launch_bounds__(256) void mm_alpha(const float* __restrict__ in, const float* __restrict__ W,
                                                const float* __restrict__ a_s, const float* __restrict__ a_d,
                                                float* __restrict__ h, float* __restrict__ as_,
                                                float* __restrict__ ad_, int N) {
    __shared__ float Ws[DIM * DIM];
    __shared__ float asv[DIM], adv[DIM];
    int tid = threadIdx.x;
    for (int k = tid; k < DIM * DIM; k += 256) Ws[k] = W[k];
    if (tid < DIM) { asv[tid] = a_s[tid]; adv[tid] = a_d[tid]; }
    __syncthreads();
    int lane = tid & 63, wid = tid >> 6;
    int row = blockIdx.x * 4 + wid;
    if (row >= N) return;
    float xv = in[row * DIM + lane];
    float acc = 0.f;
    #pragma unroll
    for (int k = 0; k < DIM; ++k) acc += __shfl(xv, k) * Ws[k * DIM + lane];
    h[row * DIM + lane] = acc;
    float s1 = acc * asv[lane], s2 = acc * adv[lane];
    #pragma unroll
    for (int m = 32; m >= 1; m >>= 1) { s1 += __shfl_xor(s1, m); s2 += __shfl_xor(s2, m); }
    if (lane == 0) { as_[row] = s1; ad_[row] = s2; }
}

// ---------------- per-node softmax-aggregate + bias + l2norm + relu ----------------
// Wave per node. Pass 2 processes 4 edges/iteration: lane = esub*16 + fg,
// each lane loads a float4 of its edge's h row (1 KB/wave/iter in flight).
__global__ __launch_bounds__(256) void gat_agg(const float* __restrict__ h, const float* __restrict__ as_,
                                               const float* __restrict__ ad_, const int* __restrict__ offs,
                                               const int* __restrict__ csr, const float* __restrict__ bias,
                                               float* __restrict__ out, int N) {
    int tid = threadIdx.x, lane = tid & 63, wid = tid >> 6;
    int node = blockIdx.x * 4 + wid;
    if (node >= N) return;
    int start = offs[node], end = offs[node + 1];
    float adi = ad_[node];
    // pass 1: segment max (lane-parallel over edges)
    float m = -1e30f;
    for (int t = start + lane; t < end; t += 64) {
        float e = as_[csr[t]] + adi;
        e = (e > 0.f) ? e : 0.2f * e;
        m = fmaxf(m, e);
    }
    #pragma unroll
    for (int d = 32; d >= 1; d >>= 1) m = fmaxf(m, __shfl_xor(m, d));
    // pass 2: 4 edges in flight, 16 lanes (fg groups) per edge
    int esub = lane >> 4, fg = lane & 15;
    float a0 = 0.f, a1 = 0.f, a2 = 0.f, a3 = 0.f, s = 0.f;
    for (int t0 = start; t0 < end; t0 += 4) {
        int t = t0 + esub;
        float w = 0.f; int src = 0;
        if (t < end) {
            src = csr[t];
            float e = as_[src] + adi;
            e = (e > 0.f) ? e : 0.2f * e;
            w = expf(e - m);
        }
        const float4 hv = *(const float4*)(h + ((size_t)src << 6) + (fg << 2));
        a0 += w * hv.x; a1 += w * hv.y; a2 += w * hv.z; a3 += w * hv.w;
        s += w;
    }
    // reduce across the 4 esub groups (lanes xor 16, 32)
    #pragma unroll
    for (int d = 16; d <= 32; d <<= 1) {
        a0 += __shfl_xor(a0, d); a1 += __shfl_xor(a1, d);
        a2 += __shfl_xor(a2, d); a3 += __shfl_xor(a3, d);
        s  += __shfl_xor(s, d);
    }
    float inv = 1.f / (s + 1e-16f);
    const float4 bv = *(const float4*)(bias + (fg << 2));
    float o0 = a0 * inv + bv.x, o1 = a1 * inv + bv.y, o2 = a2 * inv + bv.z, o3 = a3 * inv + bv.w;
    float n2 = o0 * o0 + o1 * o1 + o2 * o2 + o3 * o3;
    #pragma unroll
    for (int d = 1; d <= 8; d <<= 1) n2 += __shfl_xor(n2, d);   // across fg groups
    float innrm = 1.f / fmaxf(sqrtf(n2), 1e-12f);
    if (esub == 0) {
        float4 o;
        o.x = fmaxf(o0 * innrm, 0.f); o.y = fmaxf(o1 * innrm, 0.f);
        o.z = fmaxf(o2 * innrm, 0.f); o.w = fmaxf(o3 * innrm, 0.f);
        *(float4*)(out + ((size_t)node << 6) + (fg << 2)) = o;
    }
}

// ---------------- pooling ----------------
__global__ void graph_bounds(const int* __restrict__ batch, int N, int* __restrict__ gstart) {
    int g = threadIdx.x;
    if (g > GNUM) return;
    int lo = 0, hi = N;
    while (lo < hi) { int mid = (lo + hi) >> 1; if (batch[mid] < g) lo = mid + 1; else hi = mid; }
    gstart[g] = lo;
}

#define POOL_CHUNK 8
__global__ __launch_bounds__(64) void pool_kernel(const float* __restrict__ h, const int* __restrict__ gstart,
                                                  float* __restrict__ g) {
    int gid = blockIdx.x / POOL_CHUNK, c = blockIdx.x % POOL_CHUNK;
    int lane = threadIdx.x;
    int s = gstart[gid], e = gstart[gid + 1];
    float acc = 0.f;
    for (int i = s + c; i < e; i += POOL_CHUNK) acc += h[i * DIM + lane];
    atomicAdd(&g[gid * DIM + lane], acc);
}

// ---------------- MLP head + log_softmax ----------------
__global__ __launch_bounds__(64) void mlp_kernel(const float* __restrict__ g,
                                                 const float* __restrict__ fc1w, const float* __restrict__ fc1b,
                                                 const float* __restrict__ fc2w, const float* __restrict__ fc2b,
                                                 float* __restrict__ out) {
    __shared__ float W1[DIM * DIM];
    __shared__ float tbuf[DIM];
    __shared__ float obuf[CNUM];
    int lane = threadIdx.x, gid = blockIdx.x;
    for (int k = lane; k < DIM * DIM; k += 64) W1[k] = fc1w[k];
    __syncthreads();
    float gv = g[gid * DIM + lane];
    float t = fc1b[lane];
    #pragma unroll
    for (int k = 0; k < DIM; ++k) t += __shfl(gv, k) * W1[k * DIM + lane];
    t = fmaxf(t, 0.f);
    tbuf[lane] = t;
    __syncthreads();
    if (lane < CNUM) {
        float o = fc2b[lane];
        #pragma unroll
        for (int k = 0; k < DIM; ++k) o += tbuf[k] * fc2w[k * CNUM + lane];
        obuf[lane] = o;
    }
    __syncthreads();
    if (lane < CNUM) {
        float mx = obuf[0];
        #pragma unroll
        for (int k = 1; k < CNUM; ++k) mx = fmaxf(mx, obuf[k]);
        float s = 0.f;
        #pragma unroll
        for (int k = 0; k < CNUM; ++k) s += expf(obuf[k] - mx);
        out[gid * CNUM + lane] = obuf[lane] - mx - logf(s);
    }
}

// ---------------- launch ----------------
static inline size_t align256(size_t x) { return (x + 255) & ~size_t(255); }

extern "C" void kernel_launch(void* const* d_in, const int* in_sizes, int n_in,
                              void* d_out, int out_size, void* d_ws, size_t ws_size,
                              hipStream_t stream) {
    const float* x     = (const float*)d_in[0];
    const int*   ei    = (const int*)d_in[1];
    const int*   batch = (const int*)d_in[2];
    const float* w1  = (const float*)d_in[3];
    const float* as1 = (const float*)d_in[4];
    const float* ad1 = (const float*)d_in[5];
    const float* b1  = (const float*)d_in[6];
    const float* w2  = (const float*)d_in[7];
    const float* as2 = (const float*)d_in[8];
    const float* ad2 = (const float*)d_in[9];
    const float* b2  = (const float*)d_in[10];
    const float* w3  = (const float*)d_in[11];
    const float* as3 = (const float*)d_in[12];
    const float* ad3 = (const float*)d_in[13];
    const float* b3  = (const float*)d_in[14];
    const float* fc1w = (const float*)d_in[15];
    const float* fc1b = (const float*)d_in[16];
    const float* fc2w = (const float*)d_in[17];
    const float* fc2b = (const float*)d_in[18];
    float* out = (float*)d_out;

    int N  = in_sizes[0] / DIM;
    int E  = in_sizes[1] / 2;
    int EP = E + N;
    int nb = (N + 255) / 256;   // scan blocks (<= 256 for N <= 65536)

    // workspace carve
    char* p = (char*)d_ws;
    float* hA   = (float*)p; p += align256(sizeof(float) * (size_t)N * DIM);
    float* hB   = (float*)p; p += align256(sizeof(float) * (size_t)N * DIM);
    float* as_  = (float*)p; p += align256(sizeof(float) * (size_t)N);
    float* ad_  = (float*)p; p += align256(sizeof(float) * (size_t)N);
    int*   deg  = (int*)p;   p += align256(sizeof(int) * (size_t)N);
    int*   cur  = (int*)p;   p += align256(sizeof(int) * (size_t)N);
    int*   offs = (int*)p;   p += align256(sizeof(int) * (size_t)(N + 1));
    int*   csr  = (int*)p;   p += align256(sizeof(int) * (size_t)EP);
    int*   part = (int*)p;   p += align256(sizeof(int) * (size_t)nb);
    int*   gst  = (int*)p;   p += align256(sizeof(int) * (size_t)(GNUM + 1));
    float* gpl  = (float*)p; p += align256(sizeof(float) * GNUM * DIM);

    int nblk = (N + 3) / 4;

    // CSR build (dst-grouped; layer-invariant)
    zero2_kernel<<<nb, 256, 0, stream>>>(deg, cur, N);
    deg_kernel<<<(EP + 255) / 256, 256, 0, stream>>>(ei, E, N, deg);
    scan_blocks<<<nb, 256, 0, stream>>>(deg, part, N);
    scan_top<<<1, 256, 0, stream>>>(part, nb);
    scan_down<<<nb, 256, 0, stream>>>(deg, part, offs, N);
    fill_kernel<<<(EP + 255) / 256, 256, 0, stream>>>(ei, E, N, offs, cur, csr);
    graph_bounds<<<1, 512, 0, stream>>>(batch, N, gst);

    // layer 1
    mm_alpha<<<nblk, 256, 0, stream>>>(x, w1, as1, ad1, hA, as_, ad_, N);
    gat_agg<<<nblk, 256, 0, stream>>>(hA, as_, ad_, offs, csr, b1, hB, N);
    // layer 2
    mm_alpha<<<nblk, 256, 0, stream>>>(hB, w2, as2, ad2, hA, as_, ad_, N);
    gat_agg<<<nblk, 256, 0, stream>>>(hA, as_, ad_, offs, csr, b2, hB, N);
    // layer 3
    mm_alpha<<<nblk, 256, 0, stream>>>(hB, w3, as3, ad3, hA, as_, ad_, N);
    gat_agg<<<nblk, 256, 0, stream>>>(hA, as_, ad_, offs, csr, b3, hB, N);

    // pool + head
    zero_kernel<<<(GNUM * DIM + 255) / 256, 256, 0, stream>>>((int*)gpl, GNUM * DIM);
    pool_kernel<<<GNUM * POOL_CHUNK, 64, 0, stream>>>(hB, gst, gpl);
    mlp_kernel<<<GNUM, 64, 0, stream>>>(gpl, fc1w, fc1b, fc2w, fc2b, out);
}

// Round 4
// 406.886 us; speedup vs baseline: 1.7181x; 1.2866x over previous
//
#include <hip/hip_runtime.h>
#include <hip/hip_bf16.h>
#include <math.h>

#define DIM 64
#define GNUM 256
#define CNUM 10

// ---------------- utility ----------------
__global__ void zero2_kernel(int* __restrict__ a, int* __restrict__ b, int n) {
    int i = blockIdx.x * blockDim.x + threadIdx.x;
    if (i < n) { a[i] = 0; b[i] = 0; }
}
__global__ void zero_kernel(int* __restrict__ p, int n) {
    int i = blockIdx.x * blockDim.x + threadIdx.x;
    if (i < n) p[i] = 0;
}

// ---------------- CSR build ----------------
__global__ void deg_kernel(const int* __restrict__ ei, int E, int N, int* __restrict__ deg) {
    int i = blockIdx.x * blockDim.x + threadIdx.x;
    int EP = E + N;
    if (i >= EP) return;
    int d = (i < E) ? ei[E + i] : (i - E);   // row 1 of edge_index = dst; self loops appended
    atomicAdd(&deg[d], 1);
}

// 3-phase parallel exclusive scan over deg[0..n) -> offs[0..n]
__global__ __launch_bounds__(256) void scan_blocks(const int* __restrict__ deg, int* __restrict__ part, int n) {
    __shared__ int ws[4];
    int i = blockIdx.x * 256 + threadIdx.x;
    int v = (i < n) ? deg[i] : 0;
    #pragma unroll
    for (int d = 32; d >= 1; d >>= 1) v += __shfl_xor(v, d);
    if ((threadIdx.x & 63) == 0) ws[threadIdx.x >> 6] = v;
    __syncthreads();
    if (threadIdx.x == 0) part[blockIdx.x] = ws[0] + ws[1] + ws[2] + ws[3];
}

__global__ __launch_bounds__(256) void scan_top(int* __restrict__ part, int nb) {
    // exclusive scan of part[0..nb) in place; nb <= 256
    int tid = threadIdx.x, lane = tid & 63, wid = tid >> 6;
    __shared__ int ws[4];
    int v = (tid < nb) ? part[tid] : 0;
    int x = v;
    #pragma unroll
    for (int d = 1; d < 64; d <<= 1) { int t = __shfl_up(x, d); if (lane >= d) x += t; }
    if (lane == 63) ws[wid] = x;
    __syncthreads();
    int add = 0;
    for (int w = 0; w < wid; ++w) add += ws[w];
    if (tid < nb) part[tid] = add + x - v;
}

__global__ __launch_bounds__(256) void scan_down(const int* __restrict__ deg, const int* __restrict__ part,
                                                 int* __restrict__ offs, int n) {
    __shared__ int ws[4];
    int tid = threadIdx.x, lane = tid & 63, wid = tid >> 6;
    int i = blockIdx.x * 256 + tid;
    int v = (i < n) ? deg[i] : 0;
    int x = v;
    #pragma unroll
    for (int d = 1; d < 64; d <<= 1) { int t = __shfl_up(x, d); if (lane >= d) x += t; }
    if (lane == 63) ws[wid] = x;
    __syncthreads();
    int add = part[blockIdx.x];
    for (int w = 0; w < wid; ++w) add += ws[w];
    if (i < n) offs[i] = add + x - v;
    if (i == n - 1) offs[n] = add + x;
}

__global__ void fill_kernel(const int* __restrict__ ei, int E, int N,
                            const int* __restrict__ offs, int* __restrict__ cursor,
                            int* __restrict__ csr_src) {
    int i = blockIdx.x * blockDim.x + threadIdx.x;
    int EP = E + N;
    if (i >= EP) return;
    int s, d;
    if (i < E) { s = ei[i]; d = ei[E + i]; } else { s = i - E; d = i - E; }
    int p = offs[d] + atomicAdd(&cursor[d], 1);
    csr_src[p] = s;
}

// ---------------- h = in @ W ; alpha_s = h.a_s ; alpha_d = h.a_d ----------------
// FMA-dense: lane holds W[:,lane] in 64 VGPRs; x row read via wave-uniform
// scalar loads (readfirstlane row -> s_load), consumed as SGPR operand of
// v_fma. Zero DS ops in the matmul inner loop (R3: old version issued 128
// DS ops per 64 FMAs -> LDS-pipe bound at 64.6 us).
__global__ __launch_bounds__(256) void mm_alpha(const float* __restrict__ in, const float* __restrict__ W,
                                                const float* __restrict__ a_s, const float* __restrict__ a_d,
                                                float* __restrict__ h, float* __restrict__ as_,
                                                float* __restrict__ ad_, int N) {
    int lane = threadIdx.x & 63, wid = threadIdx.x >> 6;
    int gwave = blockIdx.x * 4 + wid;
    int nwaves = gridDim.x * 4;
    float Wr[DIM];
    #pragma unroll
    for (int k = 0; k < DIM; ++k) Wr[k] = W[k * DIM + lane];
    float asl = a_s[lane], adl = a_d[lane];
    for (int row = gwave; row < N; row += nwaves) {
        int urow = __builtin_amdgcn_readfirstlane(row);
        const float* xr = in + ((size_t)urow << 6);
        float acc = 0.f;
        #pragma unroll
        for (int k = 0; k < DIM; ++k) acc += xr[k] * Wr[k];
        h[((size_t)urow << 6) + lane] = acc;
        float s1 = acc * asl, s2 = acc * adl;
        #pragma unroll
        for (int m = 32; m >= 1; m >>= 1) { s1 += __shfl_xor(s1, m); s2 += __shfl_xor(s2, m); }
        if (lane == 0) { as_[urow] = s1; ad_[urow] = s2; }
    }
}

// ---------------- per-node softmax-aggregate + bias + l2norm + relu ----------------
// Wave per node. Pass 2 processes 4 edges/iteration: lane = esub*16 + fg,
// each lane loads a float4 of its edge's h row (1 KB/wave/iter in flight).
__global__ __launch_bounds__(256) void gat_agg(const float* __restrict__ h, const float* __restrict__ as_,
                                               const float* __restrict__ ad_, const int* __restrict__ offs,
                                               const int* __restrict__ csr, const float* __restrict__ bias,
                                               float* __restrict__ out, int N) {
    int tid = threadIdx.x, lane = tid & 63, wid = tid >> 6;
    int node = blockIdx.x * 4 + wid;
    if (node >= N) return;
    int start = offs[node], end = offs[node + 1];
    float adi = ad_[node];
    // pass 1: segment max (lane-parallel over edges)
    float m = -1e30f;
    for (int t = start + lane; t < end; t += 64) {
        float e = as_[csr[t]] + adi;
        e = (e > 0.f) ? e : 0.2f * e;
        m = fmaxf(m, e);
    }
    #pragma unroll
    for (int d = 32; d >= 1; d >>= 1) m = fmaxf(m, __shfl_xor(m, d));
    // pass 2: 4 edges in flight, 16 lanes (fg groups) per edge
    int esub = lane >> 4, fg = lane & 15;
    float a0 = 0.f, a1 = 0.f, a2 = 0.f, a3 = 0.f, s = 0.f;
    for (int t0 = start; t0 < end; t0 += 4) {
        int t = t0 + esub;
        float w = 0.f; int src = 0;
        if (t < end) {
            src = csr[t];
            float e = as_[src] + adi;
            e = (e > 0.f) ? e : 0.2f * e;
            w = expf(e - m);
        }
        const float4 hv = *(const float4*)(h + ((size_t)src << 6) + (fg << 2));
        a0 += w * hv.x; a1 += w * hv.y; a2 += w * hv.z; a3 += w * hv.w;
        s += w;
    }
    // reduce across the 4 esub groups (lanes xor 16, 32)
    #pragma unroll
    for (int d = 16; d <= 32; d <<= 1) {
        a0 += __shfl_xor(a0, d); a1 += __shfl_xor(a1, d);
        a2 += __shfl_xor(a2, d); a3 += __shfl_xor(a3, d);
        s  += __shfl_xor(s, d);
    }
    float inv = 1.f / (s + 1e-16f);
    const float4 bv = *(const float4*)(bias + (fg << 2));
    float o0 = a0 * inv + bv.x, o1 = a1 * inv + bv.y, o2 = a2 * inv + bv.z, o3 = a3 * inv + bv.w;
    float n2 = o0 * o0 + o1 * o1 + o2 * o2 + o3 * o3;
    #pragma unroll
    for (int d = 1; d <= 8; d <<= 1) n2 += __shfl_xor(n2, d);   // across fg groups
    float innrm = 1.f / fmaxf(sqrtf(n2), 1e-12f);
    if (esub == 0) {
        float4 o;
        o.x = fmaxf(o0 * innrm, 0.f); o.y = fmaxf(o1 * innrm, 0.f);
        o.z = fmaxf(o2 * innrm, 0.f); o.w = fmaxf(o3 * innrm, 0.f);
        *(float4*)(out + ((size_t)node << 6) + (fg << 2)) = o;
    }
}

// ---------------- pooling ----------------
__global__ void graph_bounds(const int* __restrict__ batch, int N, int* __restrict__ gstart) {
    int g = threadIdx.x;
    if (g > GNUM) return;
    int lo = 0, hi = N;
    while (lo < hi) { int mid = (lo + hi) >> 1; if (batch[mid] < g) lo = mid + 1; else hi = mid; }
    gstart[g] = lo;
}

#define POOL_CHUNK 8
__global__ __launch_bounds__(64) void pool_kernel(const float* __restrict__ h, const int* __restrict__ gstart,
                                                  float* __restrict__ g) {
    int gid = blockIdx.x / POOL_CHUNK, c = blockIdx.x % POOL_CHUNK;
    int lane = threadIdx.x;
    int s = gstart[gid], e = gstart[gid + 1];
    float acc = 0.f;
    for (int i = s + c; i < e; i += POOL_CHUNK) acc += h[i * DIM + lane];
    atomicAdd(&g[gid * DIM + lane], acc);
}

// ---------------- MLP head + log_softmax ----------------
__global__ __launch_bounds__(64) void mlp_kernel(const float* __restrict__ g,
                                                 const float* __restrict__ fc1w, const float* __restrict__ fc1b,
                                                 const float* __restrict__ fc2w, const float* __restrict__ fc2b,
                                                 float* __restrict__ out) {
    __shared__ float W1[DIM * DIM];
    __shared__ float tbuf[DIM];
    __shared__ float obuf[CNUM];
    int lane = threadIdx.x, gid = blockIdx.x;
    for (int k = lane; k < DIM * DIM; k += 64) W1[k] = fc1w[k];
    __syncthreads();
    float gv = g[gid * DIM + lane];
    float t = fc1b[lane];
    #pragma unroll
    for (int k = 0; k < DIM; ++k) t += __shfl(gv, k) * W1[k * DIM + lane];
    t = fmaxf(t, 0.f);
    tbuf[lane] = t;
    __syncthreads();
    if (lane < CNUM) {
        float o = fc2b[lane];
        #pragma unroll
        for (int k = 0; k < DIM; ++k) o += tbuf[k] * fc2w[k * CNUM + lane];
        obuf[lane] = o;
    }
    __syncthreads();
    if (lane < CNUM) {
        float mx = obuf[0];
        #pragma unroll
        for (int k = 1; k < CNUM; ++k) mx = fmaxf(mx, obuf[k]);
        float s = 0.f;
        #pragma unroll
        for (int k = 0; k < CNUM; ++k) s += expf(obuf[k] - mx);
        out[gid * CNUM + lane] = obuf[lane] - mx - logf(s);
    }
}

// ---------------- launch ----------------
static inline size_t align256(size_t x) { return (x + 255) & ~size_t(255); }

extern "C" void kernel_launch(void* const* d_in, const int* in_sizes, int n_in,
                              void* d_out, int out_size, void* d_ws, size_t ws_size,
                              hipStream_t stream) {
    const float* x     = (const float*)d_in[0];
    const int*   ei    = (const int*)d_in[1];
    const int*   batch = (const int*)d_in[2];
    const float* w1  = (const float*)d_in[3];
    const float* as1 = (const float*)d_in[4];
    const float* ad1 = (const float*)d_in[5];
    const float* b1  = (const float*)d_in[6];
    const float* w2  = (const float*)d_in[7];
    const float* as2 = (const float*)d_in[8];
    const float* ad2 = (const float*)d_in[9];
    const float* b2  = (const float*)d_in[10];
    const float* w3  = (const float*)d_in[11];
    const float* as3 = (const float*)d_in[12];
    const float* ad3 = (const float*)d_in[13];
    const float* b3  = (const float*)d_in[14];
    const float* fc1w = (const float*)d_in[15];
    const float* fc1b = (const float*)d_in[16];
    const float* fc2w = (const float*)d_in[17];
    const float* fc2b = (const float*)d_in[18];
    float* out = (float*)d_out;

    int N  = in_sizes[0] / DIM;
    int E  = in_sizes[1] / 2;
    int EP = E + N;
    int nb = (N + 255) / 256;   // scan blocks (<= 256 for N <= 65536)

    // workspace carve
    char* p = (char*)d_ws;
    float* hA   = (float*)p; p += align256(sizeof(float) * (size_t)N * DIM);
    float* hB   = (float*)p; p += align256(sizeof(float) * (size_t)N * DIM);
    float* as_  = (float*)p; p += align256(sizeof(float) * (size_t)N);
    float* ad_  = (float*)p; p += align256(sizeof(float) * (size_t)N);
    int*   deg  = (int*)p;   p += align256(sizeof(int) * (size_t)N);
    int*   cur  = (int*)p;   p += align256(sizeof(int) * (size_t)N);
    int*   offs = (int*)p;   p += align256(sizeof(int) * (size_t)(N + 1));
    int*   csr  = (int*)p;   p += align256(sizeof(int) * (size_t)EP);
    int*   part = (int*)p;   p += align256(sizeof(int) * (size_t)nb);
    int*   gst  = (int*)p;   p += align256(sizeof(int) * (size_t)(GNUM + 1));
    float* gpl  = (float*)p; p += align256(sizeof(float) * GNUM * DIM);

    int nblk = (N + 3) / 4;
    int mmblk = 1024;   // grid-stride: 4096 waves, ~12 rows each

    // CSR build (dst-grouped; layer-invariant)
    zero2_kernel<<<nb, 256, 0, stream>>>(deg, cur, N);
    deg_kernel<<<(EP + 255) / 256, 256, 0, stream>>>(ei, E, N, deg);
    scan_blocks<<<nb, 256, 0, stream>>>(deg, part, N);
    scan_top<<<1, 256, 0, stream>>>(part, nb);
    scan_down<<<nb, 256, 0, stream>>>(deg, part, offs, N);
    fill_kernel<<<(EP + 255) / 256, 256, 0, stream>>>(ei, E, N, offs, cur, csr);
    graph_bounds<<<1, 512, 0, stream>>>(batch, N, gst);

    // layer 1
    mm_alpha<<<mmblk, 256, 0, stream>>>(x, w1, as1, ad1, hA, as_, ad_, N);
    gat_agg<<<nblk, 256, 0, stream>>>(hA, as_, ad_, offs, csr, b1, hB, N);
    // layer 2
    mm_alpha<<<mmblk, 256, 0, stream>>>(hB, w2, as2, ad2, hA, as_, ad_, N);
    gat_agg<<<nblk, 256, 0, stream>>>(hA, as_, ad_, offs, csr, b2, hB, N);
    // layer 3
    mm_alpha<<<mmblk, 256, 0, stream>>>(hB, w3, as3, ad3, hA, as_, ad_, N);
    gat_agg<<<nblk, 256, 0, stream>>>(hA, as_, ad_, offs, csr, b3, hB, N);

    // pool + head
    zero_kernel<<<(GNUM * DIM + 255) / 256, 256, 0, stream>>>((int*)gpl, GNUM * DIM);
    pool_kernel<<<GNUM * POOL_CHUNK, 64, 0, stream>>>(hB, gst, gpl);
    mlp_kernel<<<GNUM, 64, 0, stream>>>(gpl, fc1w, fc1b, fc2w, fc2b, out);
}

// Round 5
// 356.250 us; speedup vs baseline: 1.9623x; 1.1421x over previous
//
#include <hip/hip_runtime.h>
#include <hip/hip_bf16.h>
#include <math.h>

#define DIM 64
#define GNUM 256
#define CNUM 10

// ---------------- utility ----------------
__global__ void zero2_kernel(int* __restrict__ a, int* __restrict__ b, int n) {
    int i = blockIdx.x * blockDim.x + threadIdx.x;
    if (i < n) { a[i] = 0; b[i] = 0; }
}

// ---------------- CSR build ----------------
__global__ void deg_kernel(const int* __restrict__ ei, int E, int N, int* __restrict__ deg) {
    int i = blockIdx.x * blockDim.x + threadIdx.x;
    int EP = E + N;
    if (i >= EP) return;
    int d = (i < E) ? ei[E + i] : (i - E);   // row 1 of edge_index = dst; self loops appended
    atomicAdd(&deg[d], 1);
}

// scan_blocks + graph_bounds + gpl zero, role-split by blockIdx.
// grid = nb (block sums) + 1 (graph_bounds) + 64 (zero gpl; 64*256 == GNUM*DIM)
__global__ __launch_bounds__(256) void scan_misc(const int* __restrict__ deg, int* __restrict__ part, int n, int nb,
                                                 const int* __restrict__ batch, int N,
                                                 int* __restrict__ gstart, float* __restrict__ gpl) {
    int bid = blockIdx.x;
    if (bid < nb) {
        __shared__ int ws[4];
        int i = bid * 256 + threadIdx.x;
        int v = (i < n) ? deg[i] : 0;
        #pragma unroll
        for (int d = 32; d >= 1; d >>= 1) v += __shfl_xor(v, d);
        if ((threadIdx.x & 63) == 0) ws[threadIdx.x >> 6] = v;
        __syncthreads();
        if (threadIdx.x == 0) part[bid] = ws[0] + ws[1] + ws[2] + ws[3];
    } else if (bid == nb) {
        for (int g = threadIdx.x; g <= GNUM; g += 256) {
            int lo = 0, hi = N;
            while (lo < hi) { int mid = (lo + hi) >> 1; if (batch[mid] < g) lo = mid + 1; else hi = mid; }
            gstart[g] = lo;
        }
    } else {
        int i = (bid - nb - 1) * 256 + threadIdx.x;
        gpl[i] = 0.f;
    }
}

// scan_down with the top-level scan fused: each block redundantly sums
// part[0..bid) (nb <= 256 for N <= 65536). Removes the scan_top dispatch.
__global__ __launch_bounds__(256) void scan_down(const int* __restrict__ deg, const int* __restrict__ part,
                                                 int* __restrict__ offs, int n) {
    __shared__ int ws[4];
    __shared__ int base_s;
    int tid = threadIdx.x, lane = tid & 63, wid = tid >> 6;
    int pv = (tid < (int)blockIdx.x) ? part[tid] : 0;
    #pragma unroll
    for (int d = 32; d >= 1; d >>= 1) pv += __shfl_xor(pv, d);
    if (lane == 0) ws[wid] = pv;
    __syncthreads();
    if (tid == 0) base_s = ws[0] + ws[1] + ws[2] + ws[3];
    __syncthreads();
    int i = blockIdx.x * 256 + tid;
    int v = (i < n) ? deg[i] : 0;
    int x = v;
    #pragma unroll
    for (int d = 1; d < 64; d <<= 1) { int t = __shfl_up(x, d); if (lane >= d) x += t; }
    if (lane == 63) ws[wid] = x;
    __syncthreads();
    int add = base_s;
    for (int w = 0; w < wid; ++w) add += ws[w];
    if (i < n) offs[i] = add + x - v;
    if (i == n - 1) offs[n] = add + x;
}

// ---------------- mm body (h = in @ W ; alpha_s = h.a_s ; alpha_d = h.a_d) ----------------
// FMA-dense: lane holds W[:,lane] in 64 VGPRs; x row read via wave-uniform
// scalar loads (readfirstlane row -> s_load), consumed as SGPR operand of v_fma.
__device__ __forceinline__ void mm_body(int bid, int nblk,
                                        const float* __restrict__ in, const float* __restrict__ W,
                                        const float* __restrict__ a_s, const float* __restrict__ a_d,
                                        float* __restrict__ h, float* __restrict__ as_,
                                        float* __restrict__ ad_, int N) {
    int lane = threadIdx.x & 63, wid = threadIdx.x >> 6;
    int gwave = bid * 4 + wid;
    int nwaves = nblk * 4;
    float Wr[DIM];
    #pragma unroll
    for (int k = 0; k < DIM; ++k) Wr[k] = W[k * DIM + lane];
    float asl = a_s[lane], adl = a_d[lane];
    for (int row = gwave; row < N; row += nwaves) {
        int urow = __builtin_amdgcn_readfirstlane(row);
        const float* xr = in + ((size_t)urow << 6);
        float acc = 0.f;
        #pragma unroll
        for (int k = 0; k < DIM; ++k) acc += xr[k] * Wr[k];
        h[((size_t)urow << 6) + lane] = acc;
        float s1 = acc * asl, s2 = acc * adl;
        #pragma unroll
        for (int m = 32; m >= 1; m >>= 1) { s1 += __shfl_xor(s1, m); s2 += __shfl_xor(s2, m); }
        if (lane == 0) { as_[urow] = s1; ad_[urow] = s2; }
    }
}

__global__ __launch_bounds__(256) void mm_alpha(const float* __restrict__ in, const float* __restrict__ W,
                                                const float* __restrict__ a_s, const float* __restrict__ a_d,
                                                float* __restrict__ h, float* __restrict__ as_,
                                                float* __restrict__ ad_, int N) {
    mm_body(blockIdx.x, gridDim.x, in, W, a_s, a_d, h, as_, ad_, N);
}

// fill (CSR scatter) + layer-1 mm, role-split: overlaps fill's atomics with the GEMM.
__global__ __launch_bounds__(256) void fill_mm(const int* __restrict__ ei, int E, int N,
                                               const int* __restrict__ offs, int* __restrict__ cursor,
                                               int* __restrict__ csr_src, int fillBlocks, int mmBlocks,
                                               const float* __restrict__ in, const float* __restrict__ W,
                                               const float* __restrict__ a_s, const float* __restrict__ a_d,
                                               float* __restrict__ h, float* __restrict__ as_,
                                               float* __restrict__ ad_) {
    int bid = blockIdx.x;
    if (bid < fillBlocks) {
        int i = bid * 256 + threadIdx.x;
        int EP = E + N;
        if (i >= EP) return;
        int s, d;
        if (i < E) { s = ei[i]; d = ei[E + i]; } else { s = i - E; d = i - E; }
        int p = offs[d] + atomicAdd(&cursor[d], 1);
        csr_src[p] = s;
    } else {
        mm_body(bid - fillBlocks, mmBlocks, in, W, a_s, a_d, h, as_, ad_, N);
    }
}

// ---------------- per-node softmax-aggregate + bias + l2norm + relu ----------------
// Wave per node. Pass 1 computes e, m, w=exp(e-m), s lane-parallel with the
// first 64 edges cached in registers (w_reg/src_reg). Pass 2 broadcasts
// w/src via __shfl (ds_bpermute) -- no recomputed exp, no csr/as_ re-reads --
// processing 8 edges/iter with two float4 gathers in flight.
__global__ __launch_bounds__(256) void gat_agg(const float* __restrict__ h, const float* __restrict__ as_,
                                               const float* __restrict__ ad_, const int* __restrict__ offs,
                                               const int* __restrict__ csr, const float* __restrict__ bias,
                                               float* __restrict__ out, int N) {
    int tid = threadIdx.x, lane = tid & 63, wid = tid >> 6;
    int node = blockIdx.x * 4 + wid;
    if (node >= N) return;
    int start = offs[node], end = offs[node + 1];
    int deg = end - start;
    float adi = ad_[node];

    int src_reg = 0;
    float e_reg = -1e30f;
    if (lane < deg) {
        src_reg = csr[start + lane];
        float e = as_[src_reg] + adi;
        e_reg = (e > 0.f) ? e : 0.2f * e;
    }
    float m = e_reg;
    for (int t = start + 64 + lane; t < end; t += 64) {   // deg>64 tail (rare)
        float e = as_[csr[t]] + adi;
        e = (e > 0.f) ? e : 0.2f * e;
        m = fmaxf(m, e);
    }
    #pragma unroll
    for (int d = 32; d >= 1; d >>= 1) m = fmaxf(m, __shfl_xor(m, d));

    float w_reg = (lane < deg) ? expf(e_reg - m) : 0.f;
    float s = w_reg;
    for (int t = start + 64 + lane; t < end; t += 64) {   // deg>64 tail (rare)
        float e = as_[csr[t]] + adi;
        e = (e > 0.f) ? e : 0.2f * e;
        s += expf(e - m);
    }
    #pragma unroll
    for (int d = 32; d >= 1; d >>= 1) s += __shfl_xor(s, d);

    // pass 2: lane = esub*16+fg; 8 edges/iter, indices i0+esub and i0+4+esub
    // are < 64 (i0 <= 56), and lanes >= deg carry w_reg==0 -> auto-masked.
    int esub = lane >> 4, fg = lane & 15;
    int dmain = deg < 64 ? deg : 64;
    float a0 = 0.f, a1 = 0.f, a2 = 0.f, a3 = 0.f;
    for (int i0 = 0; i0 < dmain; i0 += 8) {
        float wA = __shfl(w_reg, i0 + esub);
        int   sA = __shfl(src_reg, i0 + esub);
        float wB = __shfl(w_reg, i0 + 4 + esub);
        int   sB = __shfl(src_reg, i0 + 4 + esub);
        const float4 hA = *(const float4*)(h + ((size_t)sA << 6) + (fg << 2));
        const float4 hB = *(const float4*)(h + ((size_t)sB << 6) + (fg << 2));
        a0 += wA * hA.x + wB * hB.x;
        a1 += wA * hA.y + wB * hB.y;
        a2 += wA * hA.z + wB * hB.z;
        a3 += wA * hA.w + wB * hB.w;
    }
    for (int t0 = start + 64; t0 < end; t0 += 4) {        // deg>64 tail (rare)
        int t = t0 + esub;
        float w = 0.f; int src = 0;
        if (t < end) {
            src = csr[t];
            float e = as_[src] + adi;
            e = (e > 0.f) ? e : 0.2f * e;
            w = expf(e - m);
        }
        const float4 hv = *(const float4*)(h + ((size_t)src << 6) + (fg << 2));
        a0 += w * hv.x; a1 += w * hv.y; a2 += w * hv.z; a3 += w * hv.w;
    }
    #pragma unroll
    for (int d = 16; d <= 32; d <<= 1) {
        a0 += __shfl_xor(a0, d); a1 += __shfl_xor(a1, d);
        a2 += __shfl_xor(a2, d); a3 += __shfl_xor(a3, d);
    }
    float inv = 1.f / (s + 1e-16f);
    const float4 bv = *(const float4*)(bias + (fg << 2));
    float o0 = a0 * inv + bv.x, o1 = a1 * inv + bv.y, o2 = a2 * inv + bv.z, o3 = a3 * inv + bv.w;
    float n2 = o0 * o0 + o1 * o1 + o2 * o2 + o3 * o3;
    #pragma unroll
    for (int d = 1; d <= 8; d <<= 1) n2 += __shfl_xor(n2, d);   // across fg groups
    float innrm = 1.f / fmaxf(sqrtf(n2), 1e-12f);
    if (esub == 0) {
        float4 o;
        o.x = fmaxf(o0 * innrm, 0.f); o.y = fmaxf(o1 * innrm, 0.f);
        o.z = fmaxf(o2 * innrm, 0.f); o.w = fmaxf(o3 * innrm, 0.f);
        *(float4*)(out + ((size_t)node << 6) + (fg << 2)) = o;
    }
}

// ---------------- pooling ----------------
#define POOL_CHUNK 8
__global__ __launch_bounds__(64) void pool_kernel(const float* __restrict__ h, const int* __restrict__ gstart,
                                                  float* __restrict__ g) {
    int gid = blockIdx.x / POOL_CHUNK, c = blockIdx.x % POOL_CHUNK;
    int lane = threadIdx.x;
    int s = gstart[gid], e = gstart[gid + 1];
    float acc = 0.f;
    for (int i = s + c; i < e; i += POOL_CHUNK) acc += h[i * DIM + lane];
    atomicAdd(&g[gid * DIM + lane], acc);
}

// ---------------- MLP head + log_softmax ----------------
__global__ __launch_bounds__(64) void mlp_kernel(const float* __restrict__ g,
                                                 const float* __restrict__ fc1w, const float* __restrict__ fc1b,
                                                 const float* __restrict__ fc2w, const float* __restrict__ fc2b,
                                                 float* __restrict__ out) {
    __shared__ float W1[DIM * DIM];
    __shared__ float tbuf[DIM];
    __shared__ float obuf[CNUM];
    int lane = threadIdx.x, gid = blockIdx.x;
    for (int k = lane; k < DIM * DIM; k += 64) W1[k] = fc1w[k];
    __syncthreads();
    float gv = g[gid * DIM + lane];
    float t = fc1b[lane];
    #pragma unroll
    for (int k = 0; k < DIM; ++k) t += __shfl(gv, k) * W1[k * DIM + lane];
    t = fmaxf(t, 0.f);
    tbuf[lane] = t;
    __syncthreads();
    if (lane < CNUM) {
        float o = fc2b[lane];
        #pragma unroll
        for (int k = 0; k < DIM; ++k) o += tbuf[k] * fc2w[k * CNUM + lane];
        obuf[lane] = o;
    }
    __syncthreads();
    if (lane < CNUM) {
        float mx = obuf[0];
        #pragma unroll
        for (int k = 1; k < CNUM; ++k) mx = fmaxf(mx, obuf[k]);
        float s = 0.f;
        #pragma unroll
        for (int k = 0; k < CNUM; ++k) s += expf(obuf[k] - mx);
        out[gid * CNUM + lane] = obuf[lane] - mx - logf(s);
    }
}

// ---------------- launch ----------------
static inline size_t align256(size_t x) { return (x + 255) & ~size_t(255); }

extern "C" void kernel_launch(void* const* d_in, const int* in_sizes, int n_in,
                              void* d_out, int out_size, void* d_ws, size_t ws_size,
                              hipStream_t stream) {
    const float* x     = (const float*)d_in[0];
    const int*   ei    = (const int*)d_in[1];
    const int*   batch = (const int*)d_in[2];
    const float* w1  = (const float*)d_in[3];
    const float* as1 = (const float*)d_in[4];
    const float* ad1 = (const float*)d_in[5];
    const float* b1  = (const float*)d_in[6];
    const float* w2  = (const float*)d_in[7];
    const float* as2 = (const float*)d_in[8];
    const float* ad2 = (const float*)d_in[9];
    const float* b2  = (const float*)d_in[10];
    const float* w3  = (const float*)d_in[11];
    const float* as3 = (const float*)d_in[12];
    const float* ad3 = (const float*)d_in[13];
    const float* b3  = (const float*)d_in[14];
    const float* fc1w = (const float*)d_in[15];
    const float* fc1b = (const float*)d_in[16];
    const float* fc2w = (const float*)d_in[17];
    const float* fc2b = (const float*)d_in[18];
    float* out = (float*)d_out;

    int N  = in_sizes[0] / DIM;
    int E  = in_sizes[1] / 2;
    int EP = E + N;
    int nb = (N + 255) / 256;   // scan blocks (<= 256 for N <= 65536)

    // workspace carve
    char* p = (char*)d_ws;
    float* hA   = (float*)p; p += align256(sizeof(float) * (size_t)N * DIM);
    float* hB   = (float*)p; p += align256(sizeof(float) * (size_t)N * DIM);
    float* as_  = (float*)p; p += align256(sizeof(float) * (size_t)N);
    float* ad_  = (float*)p; p += align256(sizeof(float) * (size_t)N);
    int*   deg  = (int*)p;   p += align256(sizeof(int) * (size_t)N);
    int*   cur  = (int*)p;   p += align256(sizeof(int) * (size_t)N);
    int*   offs = (int*)p;   p += align256(sizeof(int) * (size_t)(N + 1));
    int*   csr  = (int*)p;   p += align256(sizeof(int) * (size_t)EP);
    int*   part = (int*)p;   p += align256(sizeof(int) * (size_t)nb);
    int*   gst  = (int*)p;   p += align256(sizeof(int) * (size_t)(GNUM + 1));
    float* gpl  = (float*)p; p += align256(sizeof(float) * GNUM * DIM);

    int nblk = (N + 3) / 4;
    int mmblk = 2048;
    int fillBlocks = (EP + 255) / 256;

    // CSR build (dst-grouped; layer-invariant), 12 dispatches total
    zero2_kernel<<<nb, 256, 0, stream>>>(deg, cur, N);
    deg_kernel<<<fillBlocks, 256, 0, stream>>>(ei, E, N, deg);
    scan_misc<<<nb + 1 + 64, 256, 0, stream>>>(deg, part, N, nb, batch, N, gst, gpl);
    scan_down<<<nb, 256, 0, stream>>>(deg, part, offs, N);
    // fill + layer-1 mm overlapped
    fill_mm<<<fillBlocks + mmblk, 256, 0, stream>>>(ei, E, N, offs, cur, csr, fillBlocks, mmblk,
                                                    x, w1, as1, ad1, hA, as_, ad_);
    gat_agg<<<nblk, 256, 0, stream>>>(hA, as_, ad_, offs, csr, b1, hB, N);
    // layer 2
    mm_alpha<<<mmblk, 256, 0, stream>>>(hB, w2, as2, ad2, hA, as_, ad_, N);
    gat_agg<<<nblk, 256, 0, stream>>>(hA, as_, ad_, offs, csr, b2, hB, N);
    // layer 3
    mm_alpha<<<mmblk, 256, 0, stream>>>(hB, w3, as3, ad3, hA, as_, ad_, N);
    gat_agg<<<nblk, 256, 0, stream>>>(hA, as_, ad_, offs, csr, b3, hB, N);

    // pool + head
    pool_kernel<<<GNUM * POOL_CHUNK, 64, 0, stream>>>(hB, gst, gpl);
    mlp_kernel<<<GNUM, 64, 0, stream>>>(gpl, fc1w, fc1b, fc2w, fc2b, out);
}

// Round 6
// 319.445 us; speedup vs baseline: 2.1884x; 1.1152x over previous
//
#include <hip/hip_runtime.h>
#include <hip/hip_bf16.h>
#include <math.h>

#define DIM 64
#define GNUM 256
#define CNUM 10

// ---------------- utility ----------------
__global__ void zero1_kernel(int* __restrict__ a, int n) {
    int i = blockIdx.x * blockDim.x + threadIdx.x;
    if (i < n) a[i] = 0;
}

// ---------------- CSR build ----------------
// Pass 1: count degree AND record each edge's within-segment rank (kills the
// second atomic pass that fill needed; R5 lesson: fill's cursor atomics +
// scattered stores were ~60 us fused).
__global__ void deg_rank_kernel(const int* __restrict__ ei, int E, int N,
                                int* __restrict__ deg, int* __restrict__ rank) {
    int i = blockIdx.x * blockDim.x + threadIdx.x;
    int EP = E + N;
    if (i >= EP) return;
    int d = (i < E) ? ei[E + i] : (i - E);   // row 1 of edge_index = dst; self loops appended
    rank[i] = atomicAdd(&deg[d], 1);
}

// scan_blocks + graph_bounds + gpl zero, role-split by blockIdx.
// grid = nb (block sums) + 1 (graph_bounds) + 64 (zero gpl; 64*256 == GNUM*DIM)
__global__ __launch_bounds__(256) void scan_misc(const int* __restrict__ deg, int* __restrict__ part, int n, int nb,
                                                 const int* __restrict__ batch, int N,
                                                 int* __restrict__ gstart, float* __restrict__ gpl) {
    int bid = blockIdx.x;
    if (bid < nb) {
        __shared__ int ws[4];
        int i = bid * 256 + threadIdx.x;
        int v = (i < n) ? deg[i] : 0;
        #pragma unroll
        for (int d = 32; d >= 1; d >>= 1) v += __shfl_xor(v, d);
        if ((threadIdx.x & 63) == 0) ws[threadIdx.x >> 6] = v;
        __syncthreads();
        if (threadIdx.x == 0) part[bid] = ws[0] + ws[1] + ws[2] + ws[3];
    } else if (bid == nb) {
        for (int g = threadIdx.x; g <= GNUM; g += 256) {
            int lo = 0, hi = N;
            while (lo < hi) { int mid = (lo + hi) >> 1; if (batch[mid] < g) lo = mid + 1; else hi = mid; }
            gstart[g] = lo;
        }
    } else {
        int i = (bid - nb - 1) * 256 + threadIdx.x;
        gpl[i] = 0.f;
    }
}

// scan_down with the top-level scan fused: each block redundantly sums
// part[0..bid) (nb <= 256 for N <= 65536).
__global__ __launch_bounds__(256) void scan_down(const int* __restrict__ deg, const int* __restrict__ part,
                                                 int* __restrict__ offs, int n) {
    __shared__ int ws[4];
    __shared__ int base_s;
    int tid = threadIdx.x, lane = tid & 63, wid = tid >> 6;
    int pv = (tid < (int)blockIdx.x) ? part[tid] : 0;
    #pragma unroll
    for (int d = 32; d >= 1; d >>= 1) pv += __shfl_xor(pv, d);
    if (lane == 0) ws[wid] = pv;
    __syncthreads();
    if (tid == 0) base_s = ws[0] + ws[1] + ws[2] + ws[3];
    __syncthreads();
    int i = blockIdx.x * 256 + tid;
    int v = (i < n) ? deg[i] : 0;
    int x = v;
    #pragma unroll
    for (int d = 1; d < 64; d <<= 1) { int t = __shfl_up(x, d); if (lane >= d) x += t; }
    if (lane == 63) ws[wid] = x;
    __syncthreads();
    int add = base_s;
    for (int w = 0; w < wid; ++w) add += ws[w];
    if (i < n) offs[i] = add + x - v;
    if (i == n - 1) offs[n] = add + x;
}

// Pass 2: atomic-free scatter using precomputed rank.
__global__ void fill2_kernel(const int* __restrict__ ei, const int* __restrict__ rank, int E, int N,
                             const int* __restrict__ offs, int* __restrict__ csr_src) {
    int i = blockIdx.x * blockDim.x + threadIdx.x;
    int EP = E + N;
    if (i >= EP) return;
    int s, d;
    if (i < E) { s = ei[i]; d = ei[E + i]; } else { s = i - E; d = i - E; }
    csr_src[offs[d] + rank[i]] = s;
}

// ---------------- tiled mm: h = in @ W ; alpha_s = h.a_s ; alpha_d = h.a_d ----------------
// 64-row x 64-col tile per block; x tile transposed into LDS with stride 68
// floats (= 17 x 16B: keeps ds_read_b128 alignment, breaks bank conflicts).
// Each thread: 4x4 register tile -> 16 FMA per 2 ds_read_b128 (R3's shuffle
// version was 0.5 FMA/DS-op; R4's scalar-load version was row-latency-bound).
#define XSTR 68
__global__ __launch_bounds__(256) void mm_tile(const float* __restrict__ in, const float* __restrict__ W,
                                               const float* __restrict__ a_s, const float* __restrict__ a_d,
                                               float* __restrict__ h, float* __restrict__ as_,
                                               float* __restrict__ ad_, int N) {
    __shared__ float Ws[DIM * DIM];
    __shared__ float xT[XSTR * DIM];
    int tid = threadIdx.x;
    int base = blockIdx.x * 64;

    // stage W (4096 floats, float4-coalesced)
    const float4* W4 = (const float4*)W;
    float4* Ws4 = (float4*)Ws;
    #pragma unroll
    for (int i = 0; i < 4; ++i) Ws4[tid + 256 * i] = W4[tid + 256 * i];

    // stage x tile transposed: thread loads row (tid>>2), k-block ((tid&3)*16)
    {
        int row = tid >> 2;
        int kb = (tid & 3) << 4;
        int grow = base + row;
        int crow = grow < N ? grow : N - 1;
        const float4* xr = (const float4*)(in + ((size_t)crow << 6) + kb);
        float4 v0 = xr[0], v1 = xr[1], v2 = xr[2], v3 = xr[3];
        xT[(kb + 0) * XSTR + row] = v0.x;  xT[(kb + 1) * XSTR + row] = v0.y;
        xT[(kb + 2) * XSTR + row] = v0.z;  xT[(kb + 3) * XSTR + row] = v0.w;
        xT[(kb + 4) * XSTR + row] = v1.x;  xT[(kb + 5) * XSTR + row] = v1.y;
        xT[(kb + 6) * XSTR + row] = v1.z;  xT[(kb + 7) * XSTR + row] = v1.w;
        xT[(kb + 8) * XSTR + row] = v2.x;  xT[(kb + 9) * XSTR + row] = v2.y;
        xT[(kb + 10) * XSTR + row] = v2.z; xT[(kb + 11) * XSTR + row] = v2.w;
        xT[(kb + 12) * XSTR + row] = v3.x; xT[(kb + 13) * XSTR + row] = v3.y;
        xT[(kb + 14) * XSTR + row] = v3.z; xT[(kb + 15) * XSTR + row] = v3.w;
    }
    __syncthreads();

    int tx = tid & 15, ty = tid >> 4;
    int c0 = tx << 2, r0 = ty << 2;
    float acc[4][4] = {{0.f}};
    #pragma unroll 8
    for (int k = 0; k < DIM; ++k) {
        float4 xv = *(const float4*)(xT + k * XSTR + r0);
        float4 wv = *(const float4*)(Ws + k * DIM + c0);
        acc[0][0] += xv.x * wv.x; acc[0][1] += xv.x * wv.y; acc[0][2] += xv.x * wv.z; acc[0][3] += xv.x * wv.w;
        acc[1][0] += xv.y * wv.x; acc[1][1] += xv.y * wv.y; acc[1][2] += xv.y * wv.z; acc[1][3] += xv.y * wv.w;
        acc[2][0] += xv.z * wv.x; acc[2][1] += xv.z * wv.y; acc[2][2] += xv.z * wv.z; acc[2][3] += xv.z * wv.w;
        acc[3][0] += xv.w * wv.x; acc[3][1] += xv.w * wv.y; acc[3][2] += xv.w * wv.z; acc[3][3] += xv.w * wv.w;
    }

    float4 av = *(const float4*)(a_s + c0);
    float4 dv = *(const float4*)(a_d + c0);
    #pragma unroll
    for (int ri = 0; ri < 4; ++ri) {
        int grow = base + r0 + ri;
        float s1 = acc[ri][0] * av.x + acc[ri][1] * av.y + acc[ri][2] * av.z + acc[ri][3] * av.w;
        float s2 = acc[ri][0] * dv.x + acc[ri][1] * dv.y + acc[ri][2] * dv.z + acc[ri][3] * dv.w;
        #pragma unroll
        for (int d = 1; d <= 8; d <<= 1) { s1 += __shfl_xor(s1, d); s2 += __shfl_xor(s2, d); }
        if (grow < N) {
            float4 o; o.x = acc[ri][0]; o.y = acc[ri][1]; o.z = acc[ri][2]; o.w = acc[ri][3];
            *(float4*)(h + ((size_t)grow << 6) + c0) = o;
            if (tx == 0) { as_[grow] = s1; ad_[grow] = s2; }
        }
    }
}

// ---------------- per-node softmax-aggregate + bias + l2norm + relu ----------------
// Wave per node. Pass 1 computes e, m, w=exp(e-m), s lane-parallel with the
// first 64 edges cached in registers. Pass 2 broadcasts w/src via __shfl,
// 8 edges/iter with two float4 gathers in flight.
__global__ __launch_bounds__(256) void gat_agg(const float* __restrict__ h, const float* __restrict__ as_,
                                               const float* __restrict__ ad_, const int* __restrict__ offs,
                                               const int* __restrict__ csr, const float* __restrict__ bias,
                                               float* __restrict__ out, int N) {
    int tid = threadIdx.x, lane = tid & 63, wid = tid >> 6;
    int node = blockIdx.x * 4 + wid;
    if (node >= N) return;
    int start = offs[node], end = offs[node + 1];
    int deg = end - start;
    float adi = ad_[node];

    int src_reg = 0;
    float e_reg = -1e30f;
    if (lane < deg) {
        src_reg = csr[start + lane];
        float e = as_[src_reg] + adi;
        e_reg = (e > 0.f) ? e : 0.2f * e;
    }
    float m = e_reg;
    for (int t = start + 64 + lane; t < end; t += 64) {   // deg>64 tail (rare)
        float e = as_[csr[t]] + adi;
        e = (e > 0.f) ? e : 0.2f * e;
        m = fmaxf(m, e);
    }
    #pragma unroll
    for (int d = 32; d >= 1; d >>= 1) m = fmaxf(m, __shfl_xor(m, d));

    float w_reg = (lane < deg) ? expf(e_reg - m) : 0.f;
    float s = w_reg;
    for (int t = start + 64 + lane; t < end; t += 64) {   // deg>64 tail (rare)
        float e = as_[csr[t]] + adi;
        e = (e > 0.f) ? e : 0.2f * e;
        s += expf(e - m);
    }
    #pragma unroll
    for (int d = 32; d >= 1; d >>= 1) s += __shfl_xor(s, d);

    int esub = lane >> 4, fg = lane & 15;
    int dmain = deg < 64 ? deg : 64;
    float a0 = 0.f, a1 = 0.f, a2 = 0.f, a3 = 0.f;
    for (int i0 = 0; i0 < dmain; i0 += 8) {
        float wA = __shfl(w_reg, i0 + esub);
        int   sA = __shfl(src_reg, i0 + esub);
        float wB = __shfl(w_reg, i0 + 4 + esub);
        int   sB = __shfl(src_reg, i0 + 4 + esub);
        const float4 hA = *(const float4*)(h + ((size_t)sA << 6) + (fg << 2));
        const float4 hB = *(const float4*)(h + ((size_t)sB << 6) + (fg << 2));
        a0 += wA * hA.x + wB * hB.x;
        a1 += wA * hA.y + wB * hB.y;
        a2 += wA * hA.z + wB * hB.z;
        a3 += wA * hA.w + wB * hB.w;
    }
    for (int t0 = start + 64; t0 < end; t0 += 4) {        // deg>64 tail (rare)
        int t = t0 + esub;
        float w = 0.f; int src = 0;
        if (t < end) {
            src = csr[t];
            float e = as_[src] + adi;
            e = (e > 0.f) ? e : 0.2f * e;
            w = expf(e - m);
        }
        const float4 hv = *(const float4*)(h + ((size_t)src << 6) + (fg << 2));
        a0 += w * hv.x; a1 += w * hv.y; a2 += w * hv.z; a3 += w * hv.w;
    }
    #pragma unroll
    for (int d = 16; d <= 32; d <<= 1) {
        a0 += __shfl_xor(a0, d); a1 += __shfl_xor(a1, d);
        a2 += __shfl_xor(a2, d); a3 += __shfl_xor(a3, d);
    }
    float inv = 1.f / (s + 1e-16f);
    const float4 bv = *(const float4*)(bias + (fg << 2));
    float o0 = a0 * inv + bv.x, o1 = a1 * inv + bv.y, o2 = a2 * inv + bv.z, o3 = a3 * inv + bv.w;
    float n2 = o0 * o0 + o1 * o1 + o2 * o2 + o3 * o3;
    #pragma unroll
    for (int d = 1; d <= 8; d <<= 1) n2 += __shfl_xor(n2, d);   // across fg groups
    float innrm = 1.f / fmaxf(sqrtf(n2), 1e-12f);
    if (esub == 0) {
        float4 o;
        o.x = fmaxf(o0 * innrm, 0.f); o.y = fmaxf(o1 * innrm, 0.f);
        o.z = fmaxf(o2 * innrm, 0.f); o.w = fmaxf(o3 * innrm, 0.f);
        *(float4*)(out + ((size_t)node << 6) + (fg << 2)) = o;
    }
}

// ---------------- pooling ----------------
#define POOL_CHUNK 8
__global__ __launch_bounds__(64) void pool_kernel(const float* __restrict__ h, const int* __restrict__ gstart,
                                                  float* __restrict__ g) {
    int gid = blockIdx.x / POOL_CHUNK, c = blockIdx.x % POOL_CHUNK;
    int lane = threadIdx.x;
    int s = gstart[gid], e = gstart[gid + 1];
    float acc = 0.f;
    for (int i = s + c; i < e; i += POOL_CHUNK) acc += h[i * DIM + lane];
    atomicAdd(&g[gid * DIM + lane], acc);
}

// ---------------- MLP head + log_softmax ----------------
__global__ __launch_bounds__(64) void mlp_kernel(const float* __restrict__ g,
                                                 const float* __restrict__ fc1w, const float* __restrict__ fc1b,
                                                 const float* __restrict__ fc2w, const float* __restrict__ fc2b,
                                                 float* __restrict__ out) {
    __shared__ float W1[DIM * DIM];
    __shared__ float tbuf[DIM];
    __shared__ float obuf[CNUM];
    int lane = threadIdx.x, gid = blockIdx.x;
    for (int k = lane; k < DIM * DIM; k += 64) W1[k] = fc1w[k];
    __syncthreads();
    float gv = g[gid * DIM + lane];
    float t = fc1b[lane];
    #pragma unroll
    for (int k = 0; k < DIM; ++k) t += __shfl(gv, k) * W1[k * DIM + lane];
    t = fmaxf(t, 0.f);
    tbuf[lane] = t;
    __syncthreads();
    if (lane < CNUM) {
        float o = fc2b[lane];
        #pragma unroll
        for (int k = 0; k < DIM; ++k) o += tbuf[k] * fc2w[k * CNUM + lane];
        obuf[lane] = o;
    }
    __syncthreads();
    if (lane < CNUM) {
        float mx = obuf[0];
        #pragma unroll
        for (int k = 1; k < CNUM; ++k) mx = fmaxf(mx, obuf[k]);
        float s = 0.f;
        #pragma unroll
        for (int k = 0; k < CNUM; ++k) s += expf(obuf[k] - mx);
        out[gid * CNUM + lane] = obuf[lane] - mx - logf(s);
    }
}

// ---------------- launch ----------------
static inline size_t align256(size_t x) { return (x + 255) & ~size_t(255); }

extern "C" void kernel_launch(void* const* d_in, const int* in_sizes, int n_in,
                              void* d_out, int out_size, void* d_ws, size_t ws_size,
                              hipStream_t stream) {
    const float* x     = (const float*)d_in[0];
    const int*   ei    = (const int*)d_in[1];
    const int*   batch = (const int*)d_in[2];
    const float* w1  = (const float*)d_in[3];
    const float* as1 = (const float*)d_in[4];
    const float* ad1 = (const float*)d_in[5];
    const float* b1  = (const float*)d_in[6];
    const float* w2  = (const float*)d_in[7];
    const float* as2 = (const float*)d_in[8];
    const float* ad2 = (const float*)d_in[9];
    const float* b2  = (const float*)d_in[10];
    const float* w3  = (const float*)d_in[11];
    const float* as3 = (const float*)d_in[12];
    const float* ad3 = (const float*)d_in[13];
    const float* b3  = (const float*)d_in[14];
    const float* fc1w = (const float*)d_in[15];
    const float* fc1b = (const float*)d_in[16];
    const float* fc2w = (const float*)d_in[17];
    const float* fc2b = (const float*)d_in[18];
    float* out = (float*)d_out;

    int N  = in_sizes[0] / DIM;
    int E  = in_sizes[1] / 2;
    int EP = E + N;
    int nb = (N + 255) / 256;   // scan blocks (<= 256 for N <= 65536)

    // workspace carve
    char* p = (char*)d_ws;
    float* hA   = (float*)p; p += align256(sizeof(float) * (size_t)N * DIM);
    float* hB   = (float*)p; p += align256(sizeof(float) * (size_t)N * DIM);
    float* as_  = (float*)p; p += align256(sizeof(float) * (size_t)N);
    float* ad_  = (float*)p; p += align256(sizeof(float) * (size_t)N);
    int*   deg  = (int*)p;   p += align256(sizeof(int) * (size_t)N);
    int*   offs = (int*)p;   p += align256(sizeof(int) * (size_t)(N + 1));
    int*   rank = (int*)p;   p += align256(sizeof(int) * (size_t)EP);
    int*   csr  = (int*)p;   p += align256(sizeof(int) * (size_t)EP);
    int*   part = (int*)p;   p += align256(sizeof(int) * (size_t)nb);
    int*   gst  = (int*)p;   p += align256(sizeof(int) * (size_t)(GNUM + 1));
    float* gpl  = (float*)p; p += align256(sizeof(float) * GNUM * DIM);

    int nblk = (N + 3) / 4;
    int nbt = (N + 63) / 64;    // mm tiles
    int epBlocks = (EP + 255) / 256;

    // CSR build (dst-grouped; layer-invariant)
    zero1_kernel<<<nb, 256, 0, stream>>>(deg, N);
    deg_rank_kernel<<<epBlocks, 256, 0, stream>>>(ei, E, N, deg, rank);
    scan_misc<<<nb + 1 + 64, 256, 0, stream>>>(deg, part, N, nb, batch, N, gst, gpl);
    scan_down<<<nb, 256, 0, stream>>>(deg, part, offs, N);
    fill2_kernel<<<epBlocks, 256, 0, stream>>>(ei, rank, E, N, offs, csr);

    // layer 1
    mm_tile<<<nbt, 256, 0, stream>>>(x, w1, as1, ad1, hA, as_, ad_, N);
    gat_agg<<<nblk, 256, 0, stream>>>(hA, as_, ad_, offs, csr, b1, hB, N);
    // layer 2
    mm_tile<<<nbt, 256, 0, stream>>>(hB, w2, as2, ad2, hA, as_, ad_, N);
    gat_agg<<<nblk, 256, 0, stream>>>(hA, as_, ad_, offs, csr, b2, hB, N);
    // layer 3
    mm_tile<<<nbt, 256, 0, stream>>>(hB, w3, as3, ad3, hA, as_, ad_, N);
    gat_agg<<<nblk, 256, 0, stream>>>(hA, as_, ad_, offs, csr, b3, hB, N);

    // pool + head
    pool_kernel<<<GNUM * POOL_CHUNK, 64, 0, stream>>>(hB, gst, gpl);
    mlp_kernel<<<GNUM, 64, 0, stream>>>(gpl, fc1w, fc1b, fc2w, fc2b, out);
}

// Round 7
// 311.245 us; speedup vs baseline: 2.2461x; 1.0263x over previous
//
#include <hip/hip_runtime.h>
#include <hip/hip_bf16.h>
#include <math.h>

#define DIM 64
#define GNUM 256
#define CNUM 10

// ---------------- CSR build ----------------
// Pass 1: count degree AND record each edge's within-segment rank.
__global__ void deg_rank_kernel(const int* __restrict__ ei, int E, int N,
                                int* __restrict__ deg, int* __restrict__ rank) {
    int i = blockIdx.x * blockDim.x + threadIdx.x;
    int EP = E + N;
    if (i >= EP) return;
    int d = (i < E) ? ei[E + i] : (i - E);   // row 1 of edge_index = dst; self loops appended
    rank[i] = atomicAdd(&deg[d], 1);
}

// scan_blocks + graph_bounds + gpl zero, role-split by blockIdx.
__global__ __launch_bounds__(256) void scan_misc(const int* __restrict__ deg, int* __restrict__ part, int n, int nb,
                                                 const int* __restrict__ batch, int N,
                                                 int* __restrict__ gstart, float* __restrict__ gpl) {
    int bid = blockIdx.x;
    if (bid < nb) {
        __shared__ int ws[4];
        int i = bid * 256 + threadIdx.x;
        int v = (i < n) ? deg[i] : 0;
        #pragma unroll
        for (int d = 32; d >= 1; d >>= 1) v += __shfl_xor(v, d);
        if ((threadIdx.x & 63) == 0) ws[threadIdx.x >> 6] = v;
        __syncthreads();
        if (threadIdx.x == 0) part[bid] = ws[0] + ws[1] + ws[2] + ws[3];
    } else if (bid == nb) {
        for (int g = threadIdx.x; g <= GNUM; g += 256) {
            int lo = 0, hi = N;
            while (lo < hi) { int mid = (lo + hi) >> 1; if (batch[mid] < g) lo = mid + 1; else hi = mid; }
            gstart[g] = lo;
        }
    } else {
        int i = (bid - nb - 1) * 256 + threadIdx.x;
        gpl[i] = 0.f;
    }
}

// scan_down with the top-level scan fused (nb <= 256 for N <= 65536).
__global__ __launch_bounds__(256) void scan_down(const int* __restrict__ deg, const int* __restrict__ part,
                                                 int* __restrict__ offs, int n) {
    __shared__ int ws[4];
    __shared__ int base_s;
    int tid = threadIdx.x, lane = tid & 63, wid = tid >> 6;
    int pv = (tid < (int)blockIdx.x) ? part[tid] : 0;
    #pragma unroll
    for (int d = 32; d >= 1; d >>= 1) pv += __shfl_xor(pv, d);
    if (lane == 0) ws[wid] = pv;
    __syncthreads();
    if (tid == 0) base_s = ws[0] + ws[1] + ws[2] + ws[3];
    __syncthreads();
    int i = blockIdx.x * 256 + tid;
    int v = (i < n) ? deg[i] : 0;
    int x = v;
    #pragma unroll
    for (int d = 1; d < 64; d <<= 1) { int t = __shfl_up(x, d); if (lane >= d) x += t; }
    if (lane == 63) ws[wid] = x;
    __syncthreads();
    int add = base_s;
    for (int w = 0; w < wid; ++w) add += ws[w];
    if (i < n) offs[i] = add + x - v;
    if (i == n - 1) offs[n] = add + x;
}

// ---------------- tiled mm body ----------------
// 64x64 tile per block; x transposed into LDS (stride 68 floats = 17x16B:
// ds_read_b128-aligned, bank-conflict-free). 4x4 register tile per thread.
#define XSTR 68
__device__ __forceinline__ void mm_tile_body(int bid,
                                             const float* __restrict__ in, const float* __restrict__ W,
                                             const float* __restrict__ a_s, const float* __restrict__ a_d,
                                             float* __restrict__ h, float* __restrict__ as_,
                                             float* __restrict__ ad_, int N) {
    __shared__ float Ws[DIM * DIM];
    __shared__ float xT[XSTR * DIM];
    int tid = threadIdx.x;
    int base = bid * 64;

    const float4* W4 = (const float4*)W;
    float4* Ws4 = (float4*)Ws;
    #pragma unroll
    for (int i = 0; i < 4; ++i) Ws4[tid + 256 * i] = W4[tid + 256 * i];

    {
        int row = tid >> 2;
        int kb = (tid & 3) << 4;
        int grow = base + row;
        int crow = grow < N ? grow : N - 1;
        const float4* xr = (const float4*)(in + ((size_t)crow << 6) + kb);
        float4 v0 = xr[0], v1 = xr[1], v2 = xr[2], v3 = xr[3];
        xT[(kb + 0) * XSTR + row] = v0.x;  xT[(kb + 1) * XSTR + row] = v0.y;
        xT[(kb + 2) * XSTR + row] = v0.z;  xT[(kb + 3) * XSTR + row] = v0.w;
        xT[(kb + 4) * XSTR + row] = v1.x;  xT[(kb + 5) * XSTR + row] = v1.y;
        xT[(kb + 6) * XSTR + row] = v1.z;  xT[(kb + 7) * XSTR + row] = v1.w;
        xT[(kb + 8) * XSTR + row] = v2.x;  xT[(kb + 9) * XSTR + row] = v2.y;
        xT[(kb + 10) * XSTR + row] = v2.z; xT[(kb + 11) * XSTR + row] = v2.w;
        xT[(kb + 12) * XSTR + row] = v3.x; xT[(kb + 13) * XSTR + row] = v3.y;
        xT[(kb + 14) * XSTR + row] = v3.z; xT[(kb + 15) * XSTR + row] = v3.w;
    }
    __syncthreads();

    int tx = tid & 15, ty = tid >> 4;
    int c0 = tx << 2, r0 = ty << 2;
    float acc[4][4] = {{0.f}};
    #pragma unroll 8
    for (int k = 0; k < DIM; ++k) {
        float4 xv = *(const float4*)(xT + k * XSTR + r0);
        float4 wv = *(const float4*)(Ws + k * DIM + c0);
        acc[0][0] += xv.x * wv.x; acc[0][1] += xv.x * wv.y; acc[0][2] += xv.x * wv.z; acc[0][3] += xv.x * wv.w;
        acc[1][0] += xv.y * wv.x; acc[1][1] += xv.y * wv.y; acc[1][2] += xv.y * wv.z; acc[1][3] += xv.y * wv.w;
        acc[2][0] += xv.z * wv.x; acc[2][1] += xv.z * wv.y; acc[2][2] += xv.z * wv.z; acc[2][3] += xv.z * wv.w;
        acc[3][0] += xv.w * wv.x; acc[3][1] += xv.w * wv.y; acc[3][2] += xv.w * wv.z; acc[3][3] += xv.w * wv.w;
    }

    float4 av = *(const float4*)(a_s + c0);
    float4 dv = *(const float4*)(a_d + c0);
    #pragma unroll
    for (int ri = 0; ri < 4; ++ri) {
        int grow = base + r0 + ri;
        float s1 = acc[ri][0] * av.x + acc[ri][1] * av.y + acc[ri][2] * av.z + acc[ri][3] * av.w;
        float s2 = acc[ri][0] * dv.x + acc[ri][1] * dv.y + acc[ri][2] * dv.z + acc[ri][3] * dv.w;
        #pragma unroll
        for (int d = 1; d <= 8; d <<= 1) { s1 += __shfl_xor(s1, d); s2 += __shfl_xor(s2, d); }
        if (grow < N) {
            float4 o; o.x = acc[ri][0]; o.y = acc[ri][1]; o.z = acc[ri][2]; o.w = acc[ri][3];
            *(float4*)(h + ((size_t)grow << 6) + c0) = o;
            if (tx == 0) { as_[grow] = s1; ad_[grow] = s2; }
        }
    }
}

__global__ __launch_bounds__(256) void mm_tile(const float* __restrict__ in, const float* __restrict__ W,
                                               const float* __restrict__ a_s, const float* __restrict__ a_d,
                                               float* __restrict__ h, float* __restrict__ as_,
                                               float* __restrict__ ad_, int N) {
    mm_tile_body(blockIdx.x, in, W, a_s, a_d, h, as_, ad_, N);
}

// layer-1 mm + atomic-free CSR scatter, role-split (R6: mm_tile is LDS-tiled,
// no wave-uniformity trick to break -> safe to fuse, unlike R5's mm_body).
__global__ __launch_bounds__(256) void mm_fill(const float* __restrict__ in, const float* __restrict__ W,
                                               const float* __restrict__ a_s, const float* __restrict__ a_d,
                                               float* __restrict__ h, float* __restrict__ as_,
                                               float* __restrict__ ad_, int N, int nbt,
                                               const int* __restrict__ ei, const int* __restrict__ rank, int E,
                                               const int* __restrict__ offs, int* __restrict__ csr_src) {
    int bid = blockIdx.x;
    if (bid < nbt) {
        mm_tile_body(bid, in, W, a_s, a_d, h, as_, ad_, N);
    } else {
        int i = (bid - nbt) * 256 + threadIdx.x;
        int EP = E + N;
        if (i >= EP) return;
        int s, d;
        if (i < E) { s = ei[i]; d = ei[E + i]; } else { s = i - E; d = i - E; }
        csr_src[offs[d] + rank[i]] = s;
    }
}

// ---------------- per-node softmax-aggregate + bias + l2norm + relu ----------------
// Wave per node. Pass 1: e, m, w=exp(e-m), s lane-parallel, first 64 edges in
// registers. Pass 2: 16 edges/iter, 4 float4 gathers in flight (R6: 2 gathers
// -> latency-bound; doubling MLP targets the ~200-900cyc gather latency).
__global__ __launch_bounds__(256) void gat_agg(const float* __restrict__ h, const float* __restrict__ as_,
                                               const float* __restrict__ ad_, const int* __restrict__ offs,
                                               const int* __restrict__ csr, const float* __restrict__ bias,
                                               float* __restrict__ out, int N) {
    int tid = threadIdx.x, lane = tid & 63, wid = tid >> 6;
    int node = blockIdx.x * 4 + wid;
    if (node >= N) return;
    int start = offs[node], end = offs[node + 1];
    int deg = end - start;
    float adi = ad_[node];

    int src_reg = 0;
    float e_reg = -1e30f;
    if (lane < deg) {
        src_reg = csr[start + lane];
        float e = as_[src_reg] + adi;
        e_reg = (e > 0.f) ? e : 0.2f * e;
    }
    float m = e_reg;
    for (int t = start + 64 + lane; t < end; t += 64) {   // deg>64 tail (rare)
        float e = as_[csr[t]] + adi;
        e = (e > 0.f) ? e : 0.2f * e;
        m = fmaxf(m, e);
    }
    #pragma unroll
    for (int d = 32; d >= 1; d >>= 1) m = fmaxf(m, __shfl_xor(m, d));

    float w_reg = (lane < deg) ? expf(e_reg - m) : 0.f;
    float s = w_reg;
    for (int t = start + 64 + lane; t < end; t += 64) {   // deg>64 tail (rare)
        float e = as_[csr[t]] + adi;
        e = (e > 0.f) ? e : 0.2f * e;
        s += expf(e - m);
    }
    #pragma unroll
    for (int d = 32; d >= 1; d >>= 1) s += __shfl_xor(s, d);

    // pass 2: lane = esub*16+fg; 16 edges/iter, shfl indices <= 48+3+12 < 64;
    // lanes >= deg carry w_reg==0 -> contributions auto-masked (src 0 safe).
    int esub = lane >> 4, fg = lane & 15;
    int dmain = deg < 64 ? deg : 64;
    float a0 = 0.f, a1 = 0.f, a2 = 0.f, a3 = 0.f;
    for (int i0 = 0; i0 < dmain; i0 += 16) {
        float wA = __shfl(w_reg, i0 + esub);
        int   sA = __shfl(src_reg, i0 + esub);
        float wB = __shfl(w_reg, i0 + 4 + esub);
        int   sB = __shfl(src_reg, i0 + 4 + esub);
        float wC = __shfl(w_reg, i0 + 8 + esub);
        int   sC = __shfl(src_reg, i0 + 8 + esub);
        float wD = __shfl(w_reg, i0 + 12 + esub);
        int   sD = __shfl(src_reg, i0 + 12 + esub);
        const float4 hA = *(const float4*)(h + ((size_t)sA << 6) + (fg << 2));
        const float4 hB = *(const float4*)(h + ((size_t)sB << 6) + (fg << 2));
        const float4 hC = *(const float4*)(h + ((size_t)sC << 6) + (fg << 2));
        const float4 hD = *(const float4*)(h + ((size_t)sD << 6) + (fg << 2));
        a0 += wA * hA.x + wB * hB.x + wC * hC.x + wD * hD.x;
        a1 += wA * hA.y + wB * hB.y + wC * hC.y + wD * hD.y;
        a2 += wA * hA.z + wB * hB.z + wC * hC.z + wD * hD.z;
        a3 += wA * hA.w + wB * hB.w + wC * hC.w + wD * hD.w;
    }
    for (int t0 = start + 64; t0 < end; t0 += 4) {        // deg>64 tail (rare)
        int t = t0 + esub;
        float w = 0.f; int src = 0;
        if (t < end) {
            src = csr[t];
            float e = as_[src] + adi;
            e = (e > 0.f) ? e : 0.2f * e;
            w = expf(e - m);
        }
        const float4 hv = *(const float4*)(h + ((size_t)src << 6) + (fg << 2));
        a0 += w * hv.x; a1 += w * hv.y; a2 += w * hv.z; a3 += w * hv.w;
    }
    #pragma unroll
    for (int d = 16; d <= 32; d <<= 1) {
        a0 += __shfl_xor(a0, d); a1 += __shfl_xor(a1, d);
        a2 += __shfl_xor(a2, d); a3 += __shfl_xor(a3, d);
    }
    float inv = 1.f / (s + 1e-16f);
    const float4 bv = *(const float4*)(bias + (fg << 2));
    float o0 = a0 * inv + bv.x, o1 = a1 * inv + bv.y, o2 = a2 * inv + bv.z, o3 = a3 * inv + bv.w;
    float n2 = o0 * o0 + o1 * o1 + o2 * o2 + o3 * o3;
    #pragma unroll
    for (int d = 1; d <= 8; d <<= 1) n2 += __shfl_xor(n2, d);   // across fg groups
    float innrm = 1.f / fmaxf(sqrtf(n2), 1e-12f);
    if (esub == 0) {
        float4 o;
        o.x = fmaxf(o0 * innrm, 0.f); o.y = fmaxf(o1 * innrm, 0.f);
        o.z = fmaxf(o2 * innrm, 0.f); o.w = fmaxf(o3 * innrm, 0.f);
        *(float4*)(out + ((size_t)node << 6) + (fg << 2)) = o;
    }
}

// ---------------- pooling ----------------
#define POOL_CHUNK 8
__global__ __launch_bounds__(64) void pool_kernel(const float* __restrict__ h, const int* __restrict__ gstart,
                                                  float* __restrict__ g) {
    int gid = blockIdx.x / POOL_CHUNK, c = blockIdx.x % POOL_CHUNK;
    int lane = threadIdx.x;
    int s = gstart[gid], e = gstart[gid + 1];
    float acc = 0.f;
    for (int i = s + c; i < e; i += POOL_CHUNK) acc += h[i * DIM + lane];
    atomicAdd(&g[gid * DIM + lane], acc);
}

// ---------------- MLP head + log_softmax ----------------
__global__ __launch_bounds__(64) void mlp_kernel(const float* __restrict__ g,
                                                 const float* __restrict__ fc1w, const float* __restrict__ fc1b,
                                                 const float* __restrict__ fc2w, const float* __restrict__ fc2b,
                                                 float* __restrict__ out) {
    __shared__ float W1[DIM * DIM];
    __shared__ float tbuf[DIM];
    __shared__ float obuf[CNUM];
    int lane = threadIdx.x, gid = blockIdx.x;
    for (int k = lane; k < DIM * DIM; k += 64) W1[k] = fc1w[k];
    __syncthreads();
    float gv = g[gid * DIM + lane];
    float t = fc1b[lane];
    #pragma unroll
    for (int k = 0; k < DIM; ++k) t += __shfl(gv, k) * W1[k * DIM + lane];
    t = fmaxf(t, 0.f);
    tbuf[lane] = t;
    __syncthreads();
    if (lane < CNUM) {
        float o = fc2b[lane];
        #pragma unroll
        for (int k = 0; k < DIM; ++k) o += tbuf[k] * fc2w[k * CNUM + lane];
        obuf[lane] = o;
    }
    __syncthreads();
    if (lane < CNUM) {
        float mx = obuf[0];
        #pragma unroll
        for (int k = 1; k < CNUM; ++k) mx = fmaxf(mx, obuf[k]);
        float s = 0.f;
        #pragma unroll
        for (int k = 0; k < CNUM; ++k) s += expf(obuf[k] - mx);
        out[gid * CNUM + lane] = obuf[lane] - mx - logf(s);
    }
}

// ---------------- launch ----------------
static inline size_t align256(size_t x) { return (x + 255) & ~size_t(255); }

extern "C" void kernel_launch(void* const* d_in, const int* in_sizes, int n_in,
                              void* d_out, int out_size, void* d_ws, size_t ws_size,
                              hipStream_t stream) {
    const float* x     = (const float*)d_in[0];
    const int*   ei    = (const int*)d_in[1];
    const int*   batch = (const int*)d_in[2];
    const float* w1  = (const float*)d_in[3];
    const float* as1 = (const float*)d_in[4];
    const float* ad1 = (const float*)d_in[5];
    const float* b1  = (const float*)d_in[6];
    const float* w2  = (const float*)d_in[7];
    const float* as2 = (const float*)d_in[8];
    const float* ad2 = (const float*)d_in[9];
    const float* b2  = (const float*)d_in[10];
    const float* w3  = (const float*)d_in[11];
    const float* as3 = (const float*)d_in[12];
    const float* ad3 = (const float*)d_in[13];
    const float* b3  = (const float*)d_in[14];
    const float* fc1w = (const float*)d_in[15];
    const float* fc1b = (const float*)d_in[16];
    const float* fc2w = (const float*)d_in[17];
    const float* fc2b = (const float*)d_in[18];
    float* out = (float*)d_out;

    int N  = in_sizes[0] / DIM;
    int E  = in_sizes[1] / 2;
    int EP = E + N;
    int nb = (N + 255) / 256;   // scan blocks (<= 256 for N <= 65536)

    // workspace carve
    char* p = (char*)d_ws;
    float* hA   = (float*)p; p += align256(sizeof(float) * (size_t)N * DIM);
    float* hB   = (float*)p; p += align256(sizeof(float) * (size_t)N * DIM);
    float* as_  = (float*)p; p += align256(sizeof(float) * (size_t)N);
    float* ad_  = (float*)p; p += align256(sizeof(float) * (size_t)N);
    int*   deg  = (int*)p;   p += align256(sizeof(int) * (size_t)N);
    int*   offs = (int*)p;   p += align256(sizeof(int) * (size_t)(N + 1));
    int*   rank = (int*)p;   p += align256(sizeof(int) * (size_t)EP);
    int*   csr  = (int*)p;   p += align256(sizeof(int) * (size_t)EP);
    int*   part = (int*)p;   p += align256(sizeof(int) * (size_t)nb);
    int*   gst  = (int*)p;   p += align256(sizeof(int) * (size_t)(GNUM + 1));
    float* gpl  = (float*)p; p += align256(sizeof(float) * GNUM * DIM);

    int nblk = (N + 3) / 4;
    int nbt = (N + 63) / 64;    // mm tiles
    int epBlocks = (EP + 255) / 256;

    // CSR build (dst-grouped; layer-invariant)
    hipMemsetAsync(deg, 0, sizeof(int) * (size_t)N, stream);
    deg_rank_kernel<<<epBlocks, 256, 0, stream>>>(ei, E, N, deg, rank);
    scan_misc<<<nb + 1 + 64, 256, 0, stream>>>(deg, part, N, nb, batch, N, gst, gpl);
    scan_down<<<nb, 256, 0, stream>>>(deg, part, offs, N);

    // layer 1 (mm + CSR scatter overlapped)
    mm_fill<<<nbt + epBlocks, 256, 0, stream>>>(x, w1, as1, ad1, hA, as_, ad_, N, nbt,
                                                ei, rank, E, offs, csr);
    gat_agg<<<nblk, 256, 0, stream>>>(hA, as_, ad_, offs, csr, b1, hB, N);
    // layer 2
    mm_tile<<<nbt, 256, 0, stream>>>(hB, w2, as2, ad2, hA, as_, ad_, N);
    gat_agg<<<nblk, 256, 0, stream>>>(hA, as_, ad_, offs, csr, b2, hB, N);
    // layer 3
    mm_tile<<<nbt, 256, 0, stream>>>(hB, w3, as3, ad3, hA, as_, ad_, N);
    gat_agg<<<nblk, 256, 0, stream>>>(hA, as_, ad_, offs, csr, b3, hB, N);

    // pool + head
    pool_kernel<<<GNUM * POOL_CHUNK, 64, 0, stream>>>(hB, gst, gpl);
    mlp_kernel<<<GNUM, 64, 0, stream>>>(gpl, fc1w, fc1b, fc2w, fc2b, out);
}

// Round 8
// 290.229 us; speedup vs baseline: 2.4087x; 1.0724x over previous
//
#include <hip/hip_runtime.h>
#include <hip/hip_bf16.h>
#include <math.h>

#define DIM 64
#define GNUM 256
#define CNUM 10

// bf16x2 pack/unpack (RNE). h is stored bf16 ONLY for the gather path;
// all alpha/softmax math stays f32 (as_/ad_ computed from f32 accumulators).
__device__ __forceinline__ unsigned bfpack(float a, float b) {
    unsigned ua = __builtin_bit_cast(unsigned, a);
    unsigned ub = __builtin_bit_cast(unsigned, b);
    ua += 0x7fffu + ((ua >> 16) & 1u);
    ub += 0x7fffu + ((ub >> 16) & 1u);
    return (ua >> 16) | (ub & 0xffff0000u);
}
__device__ __forceinline__ float bflo(unsigned u) { return __builtin_bit_cast(float, u << 16); }
__device__ __forceinline__ float bfhi(unsigned u) { return __builtin_bit_cast(float, u & 0xffff0000u); }

// ---------------- CSR build ----------------
__global__ void deg_rank_kernel(const int* __restrict__ ei, int E, int N,
                                int* __restrict__ deg, int* __restrict__ rank) {
    int i = blockIdx.x * blockDim.x + threadIdx.x;
    int EP = E + N;
    if (i >= EP) return;
    int d = (i < E) ? ei[E + i] : (i - E);   // row 1 of edge_index = dst; self loops appended
    rank[i] = atomicAdd(&deg[d], 1);
}

// scan_blocks + graph_bounds, role-split by blockIdx.
__global__ __launch_bounds__(256) void scan_misc(const int* __restrict__ deg, int* __restrict__ part, int n, int nb,
                                                 const int* __restrict__ batch, int N,
                                                 int* __restrict__ gstart) {
    int bid = blockIdx.x;
    if (bid < nb) {
        __shared__ int ws[4];
        int i = bid * 256 + threadIdx.x;
        int v = (i < n) ? deg[i] : 0;
        #pragma unroll
        for (int d = 32; d >= 1; d >>= 1) v += __shfl_xor(v, d);
        if ((threadIdx.x & 63) == 0) ws[threadIdx.x >> 6] = v;
        __syncthreads();
        if (threadIdx.x == 0) part[bid] = ws[0] + ws[1] + ws[2] + ws[3];
    } else {
        for (int g = threadIdx.x; g <= GNUM; g += 256) {
            int lo = 0, hi = N;
            while (lo < hi) { int mid = (lo + hi) >> 1; if (batch[mid] < g) lo = mid + 1; else hi = mid; }
            gstart[g] = lo;
        }
    }
}

// scan_down with the top-level scan fused (nb <= 256 for N <= 65536).
__global__ __launch_bounds__(256) void scan_down(const int* __restrict__ deg, const int* __restrict__ part,
                                                 int* __restrict__ offs, int n) {
    __shared__ int ws[4];
    __shared__ int base_s;
    int tid = threadIdx.x, lane = tid & 63, wid = tid >> 6;
    int pv = (tid < (int)blockIdx.x) ? part[tid] : 0;
    #pragma unroll
    for (int d = 32; d >= 1; d >>= 1) pv += __shfl_xor(pv, d);
    if (lane == 0) ws[wid] = pv;
    __syncthreads();
    if (tid == 0) base_s = ws[0] + ws[1] + ws[2] + ws[3];
    __syncthreads();
    int i = blockIdx.x * 256 + tid;
    int v = (i < n) ? deg[i] : 0;
    int x = v;
    #pragma unroll
    for (int d = 1; d < 64; d <<= 1) { int t = __shfl_up(x, d); if (lane >= d) x += t; }
    if (lane == 63) ws[wid] = x;
    __syncthreads();
    int add = base_s;
    for (int w = 0; w < wid; ++w) add += ws[w];
    if (i < n) offs[i] = add + x - v;
    if (i == n - 1) offs[n] = add + x;
}

// ---------------- tiled mm body ----------------
// 64x64 tile per block; x transposed into LDS (stride 68 floats). 4x4 register
// tile per thread. h written as bf16x2 (R7: gather re-fetch was FETCH-bound at
// 84MB = 6.5x h size; halving h bytes halves the dominant HBM traffic).
#define XSTR 68
__device__ __forceinline__ void mm_tile_body(int bid,
                                             const float* __restrict__ in, const float* __restrict__ W,
                                             const float* __restrict__ a_s, const float* __restrict__ a_d,
                                             unsigned* __restrict__ hb, float* __restrict__ as_,
                                             float* __restrict__ ad_, int N) {
    __shared__ float Ws[DIM * DIM];
    __shared__ float xT[XSTR * DIM];
    int tid = threadIdx.x;
    int base = bid * 64;

    const float4* W4 = (const float4*)W;
    float4* Ws4 = (float4*)Ws;
    #pragma unroll
    for (int i = 0; i < 4; ++i) Ws4[tid + 256 * i] = W4[tid + 256 * i];

    {
        int row = tid >> 2;
        int kb = (tid & 3) << 4;
        int grow = base + row;
        int crow = grow < N ? grow : N - 1;
        const float4* xr = (const float4*)(in + ((size_t)crow << 6) + kb);
        float4 v0 = xr[0], v1 = xr[1], v2 = xr[2], v3 = xr[3];
        xT[(kb + 0) * XSTR + row] = v0.x;  xT[(kb + 1) * XSTR + row] = v0.y;
        xT[(kb + 2) * XSTR + row] = v0.z;  xT[(kb + 3) * XSTR + row] = v0.w;
        xT[(kb + 4) * XSTR + row] = v1.x;  xT[(kb + 5) * XSTR + row] = v1.y;
        xT[(kb + 6) * XSTR + row] = v1.z;  xT[(kb + 7) * XSTR + row] = v1.w;
        xT[(kb + 8) * XSTR + row] = v2.x;  xT[(kb + 9) * XSTR + row] = v2.y;
        xT[(kb + 10) * XSTR + row] = v2.z; xT[(kb + 11) * XSTR + row] = v2.w;
        xT[(kb + 12) * XSTR + row] = v3.x; xT[(kb + 13) * XSTR + row] = v3.y;
        xT[(kb + 14) * XSTR + row] = v3.z; xT[(kb + 15) * XSTR + row] = v3.w;
    }
    __syncthreads();

    int tx = tid & 15, ty = tid >> 4;
    int c0 = tx << 2, r0 = ty << 2;
    float acc[4][4] = {{0.f}};
    #pragma unroll 8
    for (int k = 0; k < DIM; ++k) {
        float4 xv = *(const float4*)(xT + k * XSTR + r0);
        float4 wv = *(const float4*)(Ws + k * DIM + c0);
        acc[0][0] += xv.x * wv.x; acc[0][1] += xv.x * wv.y; acc[0][2] += xv.x * wv.z; acc[0][3] += xv.x * wv.w;
        acc[1][0] += xv.y * wv.x; acc[1][1] += xv.y * wv.y; acc[1][2] += xv.y * wv.z; acc[1][3] += xv.y * wv.w;
        acc[2][0] += xv.z * wv.x; acc[2][1] += xv.z * wv.y; acc[2][2] += xv.z * wv.z; acc[2][3] += xv.z * wv.w;
        acc[3][0] += xv.w * wv.x; acc[3][1] += xv.w * wv.y; acc[3][2] += xv.w * wv.z; acc[3][3] += xv.w * wv.w;
    }

    float4 av = *(const float4*)(a_s + c0);
    float4 dv = *(const float4*)(a_d + c0);
    #pragma unroll
    for (int ri = 0; ri < 4; ++ri) {
        int grow = base + r0 + ri;
        float s1 = acc[ri][0] * av.x + acc[ri][1] * av.y + acc[ri][2] * av.z + acc[ri][3] * av.w;
        float s2 = acc[ri][0] * dv.x + acc[ri][1] * dv.y + acc[ri][2] * dv.z + acc[ri][3] * dv.w;
        #pragma unroll
        for (int d = 1; d <= 8; d <<= 1) { s1 += __shfl_xor(s1, d); s2 += __shfl_xor(s2, d); }
        if (grow < N) {
            uint2 o;
            o.x = bfpack(acc[ri][0], acc[ri][1]);
            o.y = bfpack(acc[ri][2], acc[ri][3]);
            *(uint2*)(hb + ((size_t)grow << 5) + (tx << 1)) = o;
            if (tx == 0) { as_[grow] = s1; ad_[grow] = s2; }
        }
    }
}

__global__ __launch_bounds__(256) void mm_tile(const float* __restrict__ in, const float* __restrict__ W,
                                               const float* __restrict__ a_s, const float* __restrict__ a_d,
                                               unsigned* __restrict__ hb, float* __restrict__ as_,
                                               float* __restrict__ ad_, int N) {
    mm_tile_body(blockIdx.x, in, W, a_s, a_d, hb, as_, ad_, N);
}

// layer-1 mm + atomic-free CSR scatter, role-split.
__global__ __launch_bounds__(256) void mm_fill(const float* __restrict__ in, const float* __restrict__ W,
                                               const float* __restrict__ a_s, const float* __restrict__ a_d,
                                               unsigned* __restrict__ hb, float* __restrict__ as_,
                                               float* __restrict__ ad_, int N, int nbt,
                                               const int* __restrict__ ei, const int* __restrict__ rank, int E,
                                               const int* __restrict__ offs, int* __restrict__ csr_src) {
    int bid = blockIdx.x;
    if (bid < nbt) {
        mm_tile_body(bid, in, W, a_s, a_d, hb, as_, ad_, N);
    } else {
        int i = (bid - nbt) * 256 + threadIdx.x;
        int EP = E + N;
        if (i >= EP) return;
        int s, d;
        if (i < E) { s = ei[i]; d = ei[E + i]; } else { s = i - E; d = i - E; }
        csr_src[offs[d] + rank[i]] = s;
    }
}

// ---------------- per-node softmax-aggregate + bias + l2norm + relu ----------------
// Wave per node; h gathered as bf16x2 (8B/lane/edge), weights/softmax in f32.
__global__ __launch_bounds__(256) void gat_agg(const unsigned* __restrict__ hb, const float* __restrict__ as_,
                                               const float* __restrict__ ad_, const int* __restrict__ offs,
                                               const int* __restrict__ csr, const float* __restrict__ bias,
                                               float* __restrict__ out, int N) {
    int tid = threadIdx.x, lane = tid & 63, wid = tid >> 6;
    int node = blockIdx.x * 4 + wid;
    if (node >= N) return;
    int start = offs[node], end = offs[node + 1];
    int deg = end - start;
    float adi = ad_[node];

    int src_reg = 0;
    float e_reg = -1e30f;
    if (lane < deg) {
        src_reg = csr[start + lane];
        float e = as_[src_reg] + adi;
        e_reg = (e > 0.f) ? e : 0.2f * e;
    }
    float m = e_reg;
    for (int t = start + 64 + lane; t < end; t += 64) {   // deg>64 tail (rare)
        float e = as_[csr[t]] + adi;
        e = (e > 0.f) ? e : 0.2f * e;
        m = fmaxf(m, e);
    }
    #pragma unroll
    for (int d = 32; d >= 1; d >>= 1) m = fmaxf(m, __shfl_xor(m, d));

    float w_reg = (lane < deg) ? expf(e_reg - m) : 0.f;
    float s = w_reg;
    for (int t = start + 64 + lane; t < end; t += 64) {   // deg>64 tail (rare)
        float e = as_[csr[t]] + adi;
        e = (e > 0.f) ? e : 0.2f * e;
        s += expf(e - m);
    }
    #pragma unroll
    for (int d = 32; d >= 1; d >>= 1) s += __shfl_xor(s, d);

    // pass 2: lane = esub*16+fg; 16 edges/iter, 4 uint2 gathers in flight;
    // lanes >= deg carry w_reg==0 -> contributions auto-masked (src 0 safe).
    int esub = lane >> 4, fg = lane & 15;
    int dmain = deg < 64 ? deg : 64;
    float a0 = 0.f, a1 = 0.f, a2 = 0.f, a3 = 0.f;
    for (int i0 = 0; i0 < dmain; i0 += 16) {
        float wA = __shfl(w_reg, i0 + esub);
        int   sA = __shfl(src_reg, i0 + esub);
        float wB = __shfl(w_reg, i0 + 4 + esub);
        int   sB = __shfl(src_reg, i0 + 4 + esub);
        float wC = __shfl(w_reg, i0 + 8 + esub);
        int   sC = __shfl(src_reg, i0 + 8 + esub);
        float wD = __shfl(w_reg, i0 + 12 + esub);
        int   sD = __shfl(src_reg, i0 + 12 + esub);
        const uint2 hA = *(const uint2*)(hb + ((size_t)sA << 5) + (fg << 1));
        const uint2 hB = *(const uint2*)(hb + ((size_t)sB << 5) + (fg << 1));
        const uint2 hC = *(const uint2*)(hb + ((size_t)sC << 5) + (fg << 1));
        const uint2 hD = *(const uint2*)(hb + ((size_t)sD << 5) + (fg << 1));
        a0 += wA * bflo(hA.x) + wB * bflo(hB.x) + wC * bflo(hC.x) + wD * bflo(hD.x);
        a1 += wA * bfhi(hA.x) + wB * bfhi(hB.x) + wC * bfhi(hC.x) + wD * bfhi(hD.x);
        a2 += wA * bflo(hA.y) + wB * bflo(hB.y) + wC * bflo(hC.y) + wD * bflo(hD.y);
        a3 += wA * bfhi(hA.y) + wB * bfhi(hB.y) + wC * bfhi(hC.y) + wD * bfhi(hD.y);
    }
    for (int t0 = start + 64; t0 < end; t0 += 4) {        // deg>64 tail (rare)
        int t = t0 + esub;
        float w = 0.f; int src = 0;
        if (t < end) {
            src = csr[t];
            float e = as_[src] + adi;
            e = (e > 0.f) ? e : 0.2f * e;
            w = expf(e - m);
        }
        const uint2 hv = *(const uint2*)(hb + ((size_t)src << 5) + (fg << 1));
        a0 += w * bflo(hv.x); a1 += w * bfhi(hv.x);
        a2 += w * bflo(hv.y); a3 += w * bfhi(hv.y);
    }
    #pragma unroll
    for (int d = 16; d <= 32; d <<= 1) {
        a0 += __shfl_xor(a0, d); a1 += __shfl_xor(a1, d);
        a2 += __shfl_xor(a2, d); a3 += __shfl_xor(a3, d);
    }
    float inv = 1.f / (s + 1e-16f);
    const float4 bv = *(const float4*)(bias + (fg << 2));
    float o0 = a0 * inv + bv.x, o1 = a1 * inv + bv.y, o2 = a2 * inv + bv.z, o3 = a3 * inv + bv.w;
    float n2 = o0 * o0 + o1 * o1 + o2 * o2 + o3 * o3;
    #pragma unroll
    for (int d = 1; d <= 8; d <<= 1) n2 += __shfl_xor(n2, d);   // across fg groups
    float innrm = 1.f / fmaxf(sqrtf(n2), 1e-12f);
    if (esub == 0) {
        float4 o;
        o.x = fmaxf(o0 * innrm, 0.f); o.y = fmaxf(o1 * innrm, 0.f);
        o.z = fmaxf(o2 * innrm, 0.f); o.w = fmaxf(o3 * innrm, 0.f);
        *(float4*)(out + ((size_t)node << 6) + (fg << 2)) = o;
    }
}

// ---------------- fused global_add_pool + MLP + log_softmax ----------------
// Block per graph: 4 waves stride the graph's node range (lane = feature),
// LDS-reduce, then wave 0 runs the 2-layer MLP + log_softmax.
__global__ __launch_bounds__(256) void pool_mlp(const float* __restrict__ h, const int* __restrict__ gstart,
                                                const float* __restrict__ fc1w, const float* __restrict__ fc1b,
                                                const float* __restrict__ fc2w, const float* __restrict__ fc2b,
                                                float* __restrict__ out) {
    __shared__ float W1[DIM * DIM];
    __shared__ float red[4 * DIM];
    __shared__ float tbuf[DIM];
    __shared__ float obuf[CNUM];
    int tid = threadIdx.x, lane = tid & 63, wv = tid >> 6;
    int gid = blockIdx.x;

    const float4* W4 = (const float4*)fc1w;
    float4* W1s = (float4*)W1;
    #pragma unroll
    for (int i = 0; i < 4; ++i) W1s[tid + 256 * i] = W4[tid + 256 * i];

    int s = gstart[gid], e = gstart[gid + 1];
    float acc = 0.f;
    for (int i = s + wv; i < e; i += 4) acc += h[((size_t)i << 6) + lane];
    red[wv * DIM + lane] = acc;
    __syncthreads();

    if (wv == 0) {
        float g = red[lane] + red[DIM + lane] + red[2 * DIM + lane] + red[3 * DIM + lane];
        float t = fc1b[lane];
        #pragma unroll
        for (int k = 0; k < DIM; ++k) t += __shfl(g, k) * W1[k * DIM + lane];
        t = fmaxf(t, 0.f);
        tbuf[lane] = t;
        // intra-wave: tbuf visible after s_waitcnt; no barrier needed within wave 0
        float o = 0.f;
        if (lane < CNUM) {
            o = fc2b[lane];
            #pragma unroll
            for (int k = 0; k < DIM; ++k) o += tbuf[k] * fc2w[k * CNUM + lane];
            obuf[lane] = o;
        }
        if (lane < CNUM) {
            float mx = obuf[0];
            #pragma unroll
            for (int k = 1; k < CNUM; ++k) mx = fmaxf(mx, obuf[k]);
            float ssum = 0.f;
            #pragma unroll
            for (int k = 0; k < CNUM; ++k) ssum += expf(obuf[k] - mx);
            out[gid * CNUM + lane] = o - mx - logf(ssum);
        }
    }
}

// ---------------- launch ----------------
static inline size_t align256(size_t x) { return (x + 255) & ~size_t(255); }

extern "C" void kernel_launch(void* const* d_in, const int* in_sizes, int n_in,
                              void* d_out, int out_size, void* d_ws, size_t ws_size,
                              hipStream_t stream) {
    const float* x     = (const float*)d_in[0];
    const int*   ei    = (const int*)d_in[1];
    const int*   batch = (const int*)d_in[2];
    const float* w1  = (const float*)d_in[3];
    const float* as1 = (const float*)d_in[4];
    const float* ad1 = (const float*)d_in[5];
    const float* b1  = (const float*)d_in[6];
    const float* w2  = (const float*)d_in[7];
    const float* as2 = (const float*)d_in[8];
    const float* ad2 = (const float*)d_in[9];
    const float* b2  = (const float*)d_in[10];
    const float* w3  = (const float*)d_in[11];
    const float* as3 = (const float*)d_in[12];
    const float* ad3 = (const float*)d_in[13];
    const float* b3  = (const float*)d_in[14];
    const float* fc1w = (const float*)d_in[15];
    const float* fc1b = (const float*)d_in[16];
    const float* fc2w = (const float*)d_in[17];
    const float* fc2b = (const float*)d_in[18];
    float* out = (float*)d_out;

    int N  = in_sizes[0] / DIM;
    int E  = in_sizes[1] / 2;
    int EP = E + N;
    int nb = (N + 255) / 256;   // scan blocks (<= 256 for N <= 65536)

    // workspace carve
    char* p = (char*)d_ws;
    unsigned* hbf = (unsigned*)p; p += align256(sizeof(unsigned) * (size_t)N * (DIM / 2));
    float* oA   = (float*)p; p += align256(sizeof(float) * (size_t)N * DIM);
    float* oB   = (float*)p; p += align256(sizeof(float) * (size_t)N * DIM);
    float* as_  = (float*)p; p += align256(sizeof(float) * (size_t)N);
    float* ad_  = (float*)p; p += align256(sizeof(float) * (size_t)N);
    int*   deg  = (int*)p;   p += align256(sizeof(int) * (size_t)N);
    int*   offs = (int*)p;   p += align256(sizeof(int) * (size_t)(N + 1));
    int*   rank = (int*)p;   p += align256(sizeof(int) * (size_t)EP);
    int*   csr  = (int*)p;   p += align256(sizeof(int) * (size_t)EP);
    int*   part = (int*)p;   p += align256(sizeof(int) * (size_t)nb);
    int*   gst  = (int*)p;   p += align256(sizeof(int) * (size_t)(GNUM + 1));

    int nblk = (N + 3) / 4;
    int nbt = (N + 63) / 64;    // mm tiles
    int epBlocks = (EP + 255) / 256;

    // CSR build (dst-grouped; layer-invariant)
    hipMemsetAsync(deg, 0, sizeof(int) * (size_t)N, stream);
    deg_rank_kernel<<<epBlocks, 256, 0, stream>>>(ei, E, N, deg, rank);
    scan_misc<<<nb + 1, 256, 0, stream>>>(deg, part, N, nb, batch, N, gst);
    scan_down<<<nb, 256, 0, stream>>>(deg, part, offs, N);

    // layer 1 (mm + CSR scatter overlapped)
    mm_fill<<<nbt + epBlocks, 256, 0, stream>>>(x, w1, as1, ad1, hbf, as_, ad_, N, nbt,
                                                ei, rank, E, offs, csr);
    gat_agg<<<nblk, 256, 0, stream>>>(hbf, as_, ad_, offs, csr, b1, oA, N);
    // layer 2
    mm_tile<<<nbt, 256, 0, stream>>>(oA, w2, as2, ad2, hbf, as_, ad_, N);
    gat_agg<<<nblk, 256, 0, stream>>>(hbf, as_, ad_, offs, csr, b2, oB, N);
    // layer 3
    mm_tile<<<nbt, 256, 0, stream>>>(oB, w3, as3, ad3, hbf, as_, ad_, N);
    gat_agg<<<nblk, 256, 0, stream>>>(hbf, as_, ad_, offs, csr, b3, oA, N);

    // fused pool + head
    pool_mlp<<<GNUM, 256, 0, stream>>>(oA, gst, fc1w, fc1b, fc2w, fc2b, out);
}

// Round 9
// 280.749 us; speedup vs baseline: 2.4900x; 1.0338x over previous
//
#include <hip/hip_runtime.h>
#include <hip/hip_bf16.h>
#include <math.h>

#define DIM 64
#define GNUM 256
#define CNUM 10

// bf16x2 pack/unpack (RNE). All intermediates (h, layer outputs) are bf16 for
// traffic; alpha/softmax math stays f32 (as_/ad_ from f32 accumulators).
__device__ __forceinline__ unsigned bfpack(float a, float b) {
    unsigned ua = __builtin_bit_cast(unsigned, a);
    unsigned ub = __builtin_bit_cast(unsigned, b);
    ua += 0x7fffu + ((ua >> 16) & 1u);
    ub += 0x7fffu + ((ub >> 16) & 1u);
    return (ua >> 16) | (ub & 0xffff0000u);
}
__device__ __forceinline__ float bflo(unsigned u) { return __builtin_bit_cast(float, u << 16); }
__device__ __forceinline__ float bfhi(unsigned u) { return __builtin_bit_cast(float, u & 0xffff0000u); }
__device__ __forceinline__ float bfs(unsigned short u) { return __builtin_bit_cast(float, (unsigned)u << 16); }

// ---------------- CSR build ----------------
__global__ void deg_rank_kernel(const int* __restrict__ ei, int E, int N,
                                int* __restrict__ deg, int* __restrict__ rank) {
    int i = blockIdx.x * blockDim.x + threadIdx.x;
    int EP = E + N;
    if (i >= EP) return;
    int d = (i < E) ? ei[E + i] : (i - E);   // row 1 of edge_index = dst; self loops appended
    rank[i] = atomicAdd(&deg[d], 1);
}

// scan_blocks + graph_bounds, role-split by blockIdx.
__global__ __launch_bounds__(256) void scan_misc(const int* __restrict__ deg, int* __restrict__ part, int n, int nb,
                                                 const int* __restrict__ batch, int N,
                                                 int* __restrict__ gstart) {
    int bid = blockIdx.x;
    if (bid < nb) {
        __shared__ int ws[4];
        int i = bid * 256 + threadIdx.x;
        int v = (i < n) ? deg[i] : 0;
        #pragma unroll
        for (int d = 32; d >= 1; d >>= 1) v += __shfl_xor(v, d);
        if ((threadIdx.x & 63) == 0) ws[threadIdx.x >> 6] = v;
        __syncthreads();
        if (threadIdx.x == 0) part[bid] = ws[0] + ws[1] + ws[2] + ws[3];
    } else {
        for (int g = threadIdx.x; g <= GNUM; g += 256) {
            int lo = 0, hi = N;
            while (lo < hi) { int mid = (lo + hi) >> 1; if (batch[mid] < g) lo = mid + 1; else hi = mid; }
            gstart[g] = lo;
        }
    }
}

// scan_down with the top-level scan fused (nb <= 256 for N <= 65536).
__global__ __launch_bounds__(256) void scan_down(const int* __restrict__ deg, const int* __restrict__ part,
                                                 int* __restrict__ offs, int n) {
    __shared__ int ws[4];
    __shared__ int base_s;
    int tid = threadIdx.x, lane = tid & 63, wid = tid >> 6;
    int pv = (tid < (int)blockIdx.x) ? part[tid] : 0;
    #pragma unroll
    for (int d = 32; d >= 1; d >>= 1) pv += __shfl_xor(pv, d);
    if (lane == 0) ws[wid] = pv;
    __syncthreads();
    if (tid == 0) base_s = ws[0] + ws[1] + ws[2] + ws[3];
    __syncthreads();
    int i = blockIdx.x * 256 + tid;
    int v = (i < n) ? deg[i] : 0;
    int x = v;
    #pragma unroll
    for (int d = 1; d < 64; d <<= 1) { int t = __shfl_up(x, d); if (lane >= d) x += t; }
    if (lane == 63) ws[wid] = x;
    __syncthreads();
    int add = base_s;
    for (int w = 0; w < wid; ++w) add += ws[w];
    if (i < n) offs[i] = add + x - v;
    if (i == n - 1) offs[n] = add + x;
}

// ---------------- tiled mm body ----------------
// 64x64 tile per block; x transposed into LDS (stride 68 floats). 4x4 register
// tile per thread. Input either f32 (layer 1) or packed bf16 (layers 2,3);
// h output always packed bf16 (R7: halves dominant gather traffic).
#define XSTR 68
template<bool BF16IN>
__device__ __forceinline__ void mm_tile_body(int bid,
                                             const void* __restrict__ in_, const float* __restrict__ W,
                                             const float* __restrict__ a_s, const float* __restrict__ a_d,
                                             unsigned* __restrict__ hb, float* __restrict__ as_,
                                             float* __restrict__ ad_, int N) {
    __shared__ float Ws[DIM * DIM];
    __shared__ float xT[XSTR * DIM];
    int tid = threadIdx.x;
    int base = bid * 64;

    const float4* W4 = (const float4*)W;
    float4* Ws4 = (float4*)Ws;
    #pragma unroll
    for (int i = 0; i < 4; ++i) Ws4[tid + 256 * i] = W4[tid + 256 * i];

    {
        int row = tid >> 2;
        int kb = (tid & 3) << 4;
        int grow = base + row;
        int crow = grow < N ? grow : N - 1;
        if (BF16IN) {
            const unsigned* xr = (const unsigned*)in_ + ((size_t)crow << 5) + (kb >> 1);
            uint4 u0 = *(const uint4*)xr;
            uint4 u1 = *(const uint4*)(xr + 4);
            xT[(kb + 0) * XSTR + row] = bflo(u0.x);  xT[(kb + 1) * XSTR + row] = bfhi(u0.x);
            xT[(kb + 2) * XSTR + row] = bflo(u0.y);  xT[(kb + 3) * XSTR + row] = bfhi(u0.y);
            xT[(kb + 4) * XSTR + row] = bflo(u0.z);  xT[(kb + 5) * XSTR + row] = bfhi(u0.z);
            xT[(kb + 6) * XSTR + row] = bflo(u0.w);  xT[(kb + 7) * XSTR + row] = bfhi(u0.w);
            xT[(kb + 8) * XSTR + row] = bflo(u1.x);  xT[(kb + 9) * XSTR + row] = bfhi(u1.x);
            xT[(kb + 10) * XSTR + row] = bflo(u1.y); xT[(kb + 11) * XSTR + row] = bfhi(u1.y);
            xT[(kb + 12) * XSTR + row] = bflo(u1.z); xT[(kb + 13) * XSTR + row] = bfhi(u1.z);
            xT[(kb + 14) * XSTR + row] = bflo(u1.w); xT[(kb + 15) * XSTR + row] = bfhi(u1.w);
        } else {
            const float4* xr = (const float4*)((const float*)in_ + ((size_t)crow << 6) + kb);
            float4 v0 = xr[0], v1 = xr[1], v2 = xr[2], v3 = xr[3];
            xT[(kb + 0) * XSTR + row] = v0.x;  xT[(kb + 1) * XSTR + row] = v0.y;
            xT[(kb + 2) * XSTR + row] = v0.z;  xT[(kb + 3) * XSTR + row] = v0.w;
            xT[(kb + 4) * XSTR + row] = v1.x;  xT[(kb + 5) * XSTR + row] = v1.y;
            xT[(kb + 6) * XSTR + row] = v1.z;  xT[(kb + 7) * XSTR + row] = v1.w;
            xT[(kb + 8) * XSTR + row] = v2.x;  xT[(kb + 9) * XSTR + row] = v2.y;
            xT[(kb + 10) * XSTR + row] = v2.z; xT[(kb + 11) * XSTR + row] = v2.w;
            xT[(kb + 12) * XSTR + row] = v3.x; xT[(kb + 13) * XSTR + row] = v3.y;
            xT[(kb + 14) * XSTR + row] = v3.z; xT[(kb + 15) * XSTR + row] = v3.w;
        }
    }
    __syncthreads();

    int tx = tid & 15, ty = tid >> 4;
    int c0 = tx << 2, r0 = ty << 2;
    float acc[4][4] = {{0.f}};
    #pragma unroll 8
    for (int k = 0; k < DIM; ++k) {
        float4 xv = *(const float4*)(xT + k * XSTR + r0);
        float4 wv = *(const float4*)(Ws + k * DIM + c0);
        acc[0][0] += xv.x * wv.x; acc[0][1] += xv.x * wv.y; acc[0][2] += xv.x * wv.z; acc[0][3] += xv.x * wv.w;
        acc[1][0] += xv.y * wv.x; acc[1][1] += xv.y * wv.y; acc[1][2] += xv.y * wv.z; acc[1][3] += xv.y * wv.w;
        acc[2][0] += xv.z * wv.x; acc[2][1] += xv.z * wv.y; acc[2][2] += xv.z * wv.z; acc[2][3] += xv.z * wv.w;
        acc[3][0] += xv.w * wv.x; acc[3][1] += xv.w * wv.y; acc[3][2] += xv.w * wv.z; acc[3][3] += xv.w * wv.w;
    }

    float4 av = *(const float4*)(a_s + c0);
    float4 dv = *(const float4*)(a_d + c0);
    #pragma unroll
    for (int ri = 0; ri < 4; ++ri) {
        int grow = base + r0 + ri;
        float s1 = acc[ri][0] * av.x + acc[ri][1] * av.y + acc[ri][2] * av.z + acc[ri][3] * av.w;
        float s2 = acc[ri][0] * dv.x + acc[ri][1] * dv.y + acc[ri][2] * dv.z + acc[ri][3] * dv.w;
        #pragma unroll
        for (int d = 1; d <= 8; d <<= 1) { s1 += __shfl_xor(s1, d); s2 += __shfl_xor(s2, d); }
        if (grow < N) {
            uint2 o;
            o.x = bfpack(acc[ri][0], acc[ri][1]);
            o.y = bfpack(acc[ri][2], acc[ri][3]);
            *(uint2*)(hb + ((size_t)grow << 5) + (tx << 1)) = o;
            if (tx == 0) { as_[grow] = s1; ad_[grow] = s2; }
        }
    }
}

__global__ __launch_bounds__(256) void mm_tile_bf(const unsigned* __restrict__ in, const float* __restrict__ W,
                                                  const float* __restrict__ a_s, const float* __restrict__ a_d,
                                                  unsigned* __restrict__ hb, float* __restrict__ as_,
                                                  float* __restrict__ ad_, int N) {
    mm_tile_body<true>(blockIdx.x, in, W, a_s, a_d, hb, as_, ad_, N);
}

// layer-1 mm (f32 input) + atomic-free CSR scatter, role-split.
__global__ __launch_bounds__(256) void mm_fill(const float* __restrict__ in, const float* __restrict__ W,
                                               const float* __restrict__ a_s, const float* __restrict__ a_d,
                                               unsigned* __restrict__ hb, float* __restrict__ as_,
                                               float* __restrict__ ad_, int N, int nbt,
                                               const int* __restrict__ ei, const int* __restrict__ rank, int E,
                                               const int* __restrict__ offs, int* __restrict__ csr_src) {
    int bid = blockIdx.x;
    if (bid < nbt) {
        mm_tile_body<false>(bid, in, W, a_s, a_d, hb, as_, ad_, N);
    } else {
        int i = (bid - nbt) * 256 + threadIdx.x;
        int EP = E + N;
        if (i >= EP) return;
        int s, d;
        if (i < E) { s = ei[i]; d = ei[E + i]; } else { s = i - E; d = i - E; }
        csr_src[offs[d] + rank[i]] = s;
    }
}

// ---------------- per-node softmax-aggregate + bias + l2norm + relu ----------------
// R8 restructure: NO max subtraction (e bounded ~±5: l2-normed inputs, exp
// can't overflow; softmax identical up to rounding) and NO pass-1 reductions —
// the denominator is accumulated in pass 2 and folded into the existing
// xor16/32 reduction. Critical path per node: csr load -> as_ gather -> exp
// -> shfl broadcast -> gathers -> one reduction tree (~half of R7's chain).
__global__ __launch_bounds__(256) void gat_agg(const unsigned* __restrict__ hb, const float* __restrict__ as_,
                                               const float* __restrict__ ad_, const int* __restrict__ offs,
                                               const int* __restrict__ csr, const float* __restrict__ bias,
                                               unsigned* __restrict__ outb, int N) {
    int tid = threadIdx.x, lane = tid & 63, wid = tid >> 6;
    int node = blockIdx.x * 4 + wid;
    if (node >= N) return;
    int start = offs[node], end = offs[node + 1];
    int deg = end - start;
    float adi = ad_[node];

    int src_reg = 0;
    float w_reg = 0.f;
    if (lane < deg) {
        src_reg = csr[start + lane];
        float e = as_[src_reg] + adi;
        e = (e > 0.f) ? e : 0.2f * e;
        w_reg = expf(e);
    }

    // pass 2: lane = esub*16+fg; 16 edges/iter, 4 uint2 gathers in flight;
    // lanes >= deg carry w_reg==0 -> contributions auto-masked (src 0 safe).
    // sw accumulates the softmax denominator (same value across fg lanes of an
    // esub group; the xor16/32 tree below sums the 4 esub groups exactly once).
    int esub = lane >> 4, fg = lane & 15;
    int dmain = deg < 64 ? deg : 64;
    float a0 = 0.f, a1 = 0.f, a2 = 0.f, a3 = 0.f, sw = 0.f;
    for (int i0 = 0; i0 < dmain; i0 += 16) {
        float wA = __shfl(w_reg, i0 + esub);
        int   sA = __shfl(src_reg, i0 + esub);
        float wB = __shfl(w_reg, i0 + 4 + esub);
        int   sB = __shfl(src_reg, i0 + 4 + esub);
        float wC = __shfl(w_reg, i0 + 8 + esub);
        int   sC = __shfl(src_reg, i0 + 8 + esub);
        float wD = __shfl(w_reg, i0 + 12 + esub);
        int   sD = __shfl(src_reg, i0 + 12 + esub);
        const uint2 hA = *(const uint2*)(hb + ((size_t)sA << 5) + (fg << 1));
        const uint2 hB = *(const uint2*)(hb + ((size_t)sB << 5) + (fg << 1));
        const uint2 hC = *(const uint2*)(hb + ((size_t)sC << 5) + (fg << 1));
        const uint2 hD = *(const uint2*)(hb + ((size_t)sD << 5) + (fg << 1));
        sw += wA + wB + wC + wD;
        a0 += wA * bflo(hA.x) + wB * bflo(hB.x) + wC * bflo(hC.x) + wD * bflo(hD.x);
        a1 += wA * bfhi(hA.x) + wB * bfhi(hB.x) + wC * bfhi(hC.x) + wD * bfhi(hD.x);
        a2 += wA * bflo(hA.y) + wB * bflo(hB.y) + wC * bflo(hC.y) + wD * bflo(hD.y);
        a3 += wA * bfhi(hA.y) + wB * bfhi(hB.y) + wC * bfhi(hC.y) + wD * bfhi(hD.y);
    }
    for (int t0 = start + 64; t0 < end; t0 += 4) {        // deg>64 tail (rare)
        int t = t0 + esub;
        float w = 0.f; int src = 0;
        if (t < end) {
            src = csr[t];
            float e = as_[src] + adi;
            e = (e > 0.f) ? e : 0.2f * e;
            w = expf(e);
        }
        const uint2 hv = *(const uint2*)(hb + ((size_t)src << 5) + (fg << 1));
        sw += w;
        a0 += w * bflo(hv.x); a1 += w * bfhi(hv.x);
        a2 += w * bflo(hv.y); a3 += w * bfhi(hv.y);
    }
    #pragma unroll
    for (int d = 16; d <= 32; d <<= 1) {
        a0 += __shfl_xor(a0, d); a1 += __shfl_xor(a1, d);
        a2 += __shfl_xor(a2, d); a3 += __shfl_xor(a3, d);
        sw += __shfl_xor(sw, d);
    }
    float inv = 1.f / (sw + 1e-16f);
    const float4 bv = *(const float4*)(bias + (fg << 2));
    float o0 = a0 * inv + bv.x, o1 = a1 * inv + bv.y, o2 = a2 * inv + bv.z, o3 = a3 * inv + bv.w;
    float n2 = o0 * o0 + o1 * o1 + o2 * o2 + o3 * o3;
    #pragma unroll
    for (int d = 1; d <= 8; d <<= 1) n2 += __shfl_xor(n2, d);   // across fg groups
    float innrm = 1.f / fmaxf(sqrtf(n2), 1e-12f);
    if (esub == 0) {
        uint2 o;
        o.x = bfpack(fmaxf(o0 * innrm, 0.f), fmaxf(o1 * innrm, 0.f));
        o.y = bfpack(fmaxf(o2 * innrm, 0.f), fmaxf(o3 * innrm, 0.f));
        *(uint2*)(outb + ((size_t)node << 5) + (fg << 1)) = o;
    }
}

// ---------------- fused global_add_pool + MLP + log_softmax ----------------
// Block per graph: 4 waves stride the graph's node range (lane = feature,
// bf16 rows), LDS-reduce, wave 0 runs the 2-layer MLP + log_softmax.
__global__ __launch_bounds__(256) void pool_mlp(const unsigned short* __restrict__ hb, const int* __restrict__ gstart,
                                                const float* __restrict__ fc1w, const float* __restrict__ fc1b,
                                                const float* __restrict__ fc2w, const float* __restrict__ fc2b,
                                                float* __restrict__ out) {
    __shared__ float W1[DIM * DIM];
    __shared__ float red[4 * DIM];
    __shared__ float tbuf[DIM];
    __shared__ float obuf[CNUM];
    int tid = threadIdx.x, lane = tid & 63, wv = tid >> 6;
    int gid = blockIdx.x;

    const float4* W4 = (const float4*)fc1w;
    float4* W1s = (float4*)W1;
    #pragma unroll
    for (int i = 0; i < 4; ++i) W1s[tid + 256 * i] = W4[tid + 256 * i];

    int s = gstart[gid], e = gstart[gid + 1];
    float acc = 0.f;
    for (int i = s + wv; i < e; i += 4) acc += bfs(hb[((size_t)i << 6) + lane]);
    red[wv * DIM + lane] = acc;
    __syncthreads();

    if (wv == 0) {
        float g = red[lane] + red[DIM + lane] + red[2 * DIM + lane] + red[3 * DIM + lane];
        float t = fc1b[lane];
        #pragma unroll
        for (int k = 0; k < DIM; ++k) t += __shfl(g, k) * W1[k * DIM + lane];
        t = fmaxf(t, 0.f);
        tbuf[lane] = t;
        float o = 0.f;
        if (lane < CNUM) {
            o = fc2b[lane];
            #pragma unroll
            for (int k = 0; k < DIM; ++k) o += tbuf[k] * fc2w[k * CNUM + lane];
            obuf[lane] = o;
        }
        if (lane < CNUM) {
            float mx = obuf[0];
            #pragma unroll
            for (int k = 1; k < CNUM; ++k) mx = fmaxf(mx, obuf[k]);
            float ssum = 0.f;
            #pragma unroll
            for (int k = 0; k < CNUM; ++k) ssum += expf(obuf[k] - mx);
            out[gid * CNUM + lane] = o - mx - logf(ssum);
        }
    }
}

// ---------------- launch ----------------
static inline size_t align256(size_t x) { return (x + 255) & ~size_t(255); }

extern "C" void kernel_launch(void* const* d_in, const int* in_sizes, int n_in,
                              void* d_out, int out_size, void* d_ws, size_t ws_size,
                              hipStream_t stream) {
    const float* x     = (const float*)d_in[0];
    const int*   ei    = (const int*)d_in[1];
    const int*   batch = (const int*)d_in[2];
    const float* w1  = (const float*)d_in[3];
    const float* as1 = (const float*)d_in[4];
    const float* ad1 = (const float*)d_in[5];
    const float* b1  = (const float*)d_in[6];
    const float* w2  = (const float*)d_in[7];
    const float* as2 = (const float*)d_in[8];
    const float* ad2 = (const float*)d_in[9];
    const float* b2  = (const float*)d_in[10];
    const float* w3  = (const float*)d_in[11];
    const float* as3 = (const float*)d_in[12];
    const float* ad3 = (const float*)d_in[13];
    const float* b3  = (const float*)d_in[14];
    const float* fc1w = (const float*)d_in[15];
    const float* fc1b = (const float*)d_in[16];
    const float* fc2w = (const float*)d_in[17];
    const float* fc2b = (const float*)d_in[18];
    float* out = (float*)d_out;

    int N  = in_sizes[0] / DIM;
    int E  = in_sizes[1] / 2;
    int EP = E + N;
    int nb = (N + 255) / 256;   // scan blocks (<= 256 for N <= 65536)

    // workspace carve
    char* p = (char*)d_ws;
    unsigned* hbf = (unsigned*)p; p += align256(sizeof(unsigned) * (size_t)N * (DIM / 2));
    unsigned* oAb = (unsigned*)p; p += align256(sizeof(unsigned) * (size_t)N * (DIM / 2));
    unsigned* oBb = (unsigned*)p; p += align256(sizeof(unsigned) * (size_t)N * (DIM / 2));
    float* as_  = (float*)p; p += align256(sizeof(float) * (size_t)N);
    float* ad_  = (float*)p; p += align256(sizeof(float) * (size_t)N);
    int*   deg  = (int*)p;   p += align256(sizeof(int) * (size_t)N);
    int*   offs = (int*)p;   p += align256(sizeof(int) * (size_t)(N + 1));
    int*   rank = (int*)p;   p += align256(sizeof(int) * (size_t)EP);
    int*   csr  = (int*)p;   p += align256(sizeof(int) * (size_t)EP);
    int*   part = (int*)p;   p += align256(sizeof(int) * (size_t)nb);
    int*   gst  = (int*)p;   p += align256(sizeof(int) * (size_t)(GNUM + 1));

    int nblk = (N + 3) / 4;
    int nbt = (N + 63) / 64;    // mm tiles
    int epBlocks = (EP + 255) / 256;

    // CSR build (dst-grouped; layer-invariant)
    hipMemsetAsync(deg, 0, sizeof(int) * (size_t)N, stream);
    deg_rank_kernel<<<epBlocks, 256, 0, stream>>>(ei, E, N, deg, rank);
    scan_misc<<<nb + 1, 256, 0, stream>>>(deg, part, N, nb, batch, N, gst);
    scan_down<<<nb, 256, 0, stream>>>(deg, part, offs, N);

    // layer 1 (mm + CSR scatter overlapped)
    mm_fill<<<nbt + epBlocks, 256, 0, stream>>>(x, w1, as1, ad1, hbf, as_, ad_, N, nbt,
                                                ei, rank, E, offs, csr);
    gat_agg<<<nblk, 256, 0, stream>>>(hbf, as_, ad_, offs, csr, b1, oAb, N);
    // layer 2
    mm_tile_bf<<<nbt, 256, 0, stream>>>(oAb, w2, as2, ad2, hbf, as_, ad_, N);
    gat_agg<<<nblk, 256, 0, stream>>>(hbf, as_, ad_, offs, csr, b2, oBb, N);
    // layer 3
    mm_tile_bf<<<nbt, 256, 0, stream>>>(oBb, w3, as3, ad3, hbf, as_, ad_, N);
    gat_agg<<<nblk, 256, 0, stream>>>(hbf, as_, ad_, offs, csr, b3, oAb, N);

    // fused pool + head (bf16 input)
    pool_mlp<<<GNUM, 256, 0, stream>>>((const unsigned short*)oAb, gst, fc1w, fc1b, fc2w, fc2b, out);
}